// Round 11
// baseline (2488.504 us; speedup 1.0000x reference)
//
#include <hip/hip_runtime.h>
#include <math.h>

typedef unsigned short u16;
typedef __attribute__((ext_vector_type(8))) short s8v;   // 8 x bf16 (4 VGPRs)
typedef __attribute__((ext_vector_type(4))) float f4v;   // MFMA accumulator
typedef __attribute__((ext_vector_type(4))) int   i4v;   // asm load payload

constexpr int kB    = 256;
constexpr int kT    = 512;
constexpr int kDIN  = 64;
constexpr int kH    = 512;
constexpr int kG3   = 1536;
constexpr int kNOUT = 128;
constexpr int kPlane = 8 * 2 * 16 * 512;   // u16 per h A-frag plane (131072)
constexpr int kXStep = 16 * 2 * 512;       // u16 per x A-frag step (16384)

#define MFMA16 __builtin_amdgcn_mfma_f32_16x16x32_bf16

__device__ __forceinline__ u16 f2bf(float f) {   // round-to-nearest-even
  union { float f; unsigned u; } v; v.f = f;
  unsigned r = (v.u + 0x7FFFu + ((v.u >> 16) & 1u)) >> 16;
  return (u16)r;
}
__device__ __forceinline__ float fsig(float x) {
  x = fminf(fmaxf(x, -30.f), 30.f);
  float e = __expf(-x);
  return __fdividef(1.f, 1.f + e);
}
__device__ __forceinline__ float ftanh(float x) {
  x = fminf(fmaxf(x, -15.f), 15.f);
  float e = __expf(-2.f * x);
  return __fdividef(1.f - e, 1.f + e);
}

// 8 A-fragment loads (this wave's HALF of the mt-region: kt = u*8 .. u*8+7),
// LLC-coherent bypass, NO trailing wait — caller pairs with explicit vmcnt.
// Halves the per-block coherent fetch vs the old per-wave 16-frag loader
// (wave pairs with equal mt used to fetch identical 16 KB twice).
__device__ __forceinline__ void load8_nw(const u16* base, i4v a[8]) {
  asm volatile(
      "global_load_dwordx4 %0, %8, off sc0 sc1\n\t"
      "global_load_dwordx4 %1, %8, off offset:1024 sc0 sc1\n\t"
      "global_load_dwordx4 %2, %8, off offset:2048 sc0 sc1\n\t"
      "global_load_dwordx4 %3, %8, off offset:3072 sc0 sc1\n\t"
      "global_load_dwordx4 %4, %9, off sc0 sc1\n\t"
      "global_load_dwordx4 %5, %9, off offset:1024 sc0 sc1\n\t"
      "global_load_dwordx4 %6, %9, off offset:2048 sc0 sc1\n\t"
      "global_load_dwordx4 %7, %9, off offset:3072 sc0 sc1"
      : "=&v"(a[0]), "=&v"(a[1]), "=&v"(a[2]), "=&v"(a[3]),
        "=&v"(a[4]), "=&v"(a[5]), "=&v"(a[6]), "=&v"(a[7])
      : "v"(base), "v"(base + 4 * 512)
      : "memory");
}

// Layer-0 publish: 4 coherent hbuf stores FIRST, then 4 plain h1pl stores,
// then vmcnt(4) — waits only the hbuf 4; h1pl drains during the barrier
// round (vmcnt retires in issue order). (Verified round-0/5 pattern.)
__device__ __forceinline__ void store_h_l0(
    u16* p0, u16* p1, u16* p2, u16* p3,
    u16* q0, u16* q1, u16* q2, u16* q3,
    unsigned v0, unsigned v1, unsigned v2, unsigned v3) {
  asm volatile(
      "global_store_short %0, %8, off sc0 sc1\n\t"
      "global_store_short %1, %9, off sc0 sc1\n\t"
      "global_store_short %2, %10, off sc0 sc1\n\t"
      "global_store_short %3, %11, off sc0 sc1\n\t"
      "global_store_short %4, %8, off\n\t"
      "global_store_short %5, %9, off\n\t"
      "global_store_short %6, %10, off\n\t"
      "global_store_short %7, %11, off\n\t"
      "s_waitcnt vmcnt(4)"
      :: "v"(p0), "v"(p1), "v"(p2), "v"(p3),
         "v"(q0), "v"(q1), "v"(q2), "v"(q3),
         "v"(v0), "v"(v1), "v"(v2), "v"(v3)
      : "memory");
}
// Layer-1: 4 coherent stores + full drain. (Verified round-0/5.)
__device__ __forceinline__ void store_h_l1(
    u16* p0, u16* p1, u16* p2, u16* p3,
    unsigned v0, unsigned v1, unsigned v2, unsigned v3) {
  asm volatile(
      "global_store_short %0, %4, off sc0 sc1\n\t"
      "global_store_short %1, %5, off sc0 sc1\n\t"
      "global_store_short %2, %6, off sc0 sc1\n\t"
      "global_store_short %3, %7, off sc0 sc1\n\t"
      "s_waitcnt vmcnt(0)"
      :: "v"(p0), "v"(p1), "v"(p2), "v"(p3),
         "v"(v0), "v"(v1), "v"(v2), "v"(v3)
      : "memory");
}

// ---------------------------------------------------------------------------
// B-frag slab for [1536][512] fp32 weights (w_hh0, w_hh1, w_ih1).
// Layout: [jt 16][f 96][lane 64][8], f = (g*2+u)*16 + kt.   (Verified r0-r10.)
// ---------------------------------------------------------------------------
__global__ void build_wslab(const float* __restrict__ w, u16* __restrict__ d) {
  int idx  = blockIdx.x * 256 + threadIdx.x;   // 0..98303
  int lane = idx & 63, fg = idx >> 6;          // fg = jt*96 + f
  int jt = fg / 96, f = fg % 96;
  int nt = f >> 4, kt = f & 15;
  int g = nt >> 1, u = nt & 1;
  int row = g * 512 + jt * 32 + u * 16 + (lane & 15);
  int k0  = kt * 32 + (lane >> 4) * 8;
  const float* src = w + (size_t)row * 512 + k0;
  u16* dst = d + ((size_t)fg) * 512 + lane * 8;
#pragma unroll
  for (int i = 0; i < 8; i++) dst[i] = f2bf(src[i]);
}

// B-frag slab for w_ih0 [1536][64]: [jt 16][f 12][lane 64][8], f=(g*2+u)*2+kt.
// (Verified r4-r10.)
__global__ void build_wslab_ih0(const float* __restrict__ w, u16* __restrict__ d) {
  int idx  = blockIdx.x * 256 + threadIdx.x;   // 0..12287
  int lane = idx & 63, fg = idx >> 6;          // fg = jt*12 + f
  int jt = fg / 12, f = fg % 12;
  int nt = f >> 1, kt = f & 1;
  int g = nt >> 1, u = nt & 1;
  int row = g * 512 + jt * 32 + u * 16 + (lane & 15);
  int k0  = kt * 32 + (lane >> 4) * 8;
  const float* src = w + (size_t)row * kDIN + k0;
  u16* dst = d + ((size_t)fg) * 512 + lane * 8;
#pragma unroll
  for (int i = 0; i < 8; i++) dst[i] = f2bf(src[i]);
}

// x [256][512][64] fp32 -> per-step A-frag planes (bf16). (Verified r4-r10.)
__global__ void build_xplane(const float* __restrict__ x, u16* __restrict__ d) {
  int idx  = blockIdx.x * 256 + threadIdx.x;   // 0..1048575
  int lane = idx & 63, fg = idx >> 6;          // fg = (T*16+m)*2+kt
  int kt = fg & 1, m = (fg >> 1) & 15, T = fg >> 5;
  int b  = m * 16 + (lane & 15);
  int k0 = kt * 32 + (lane >> 4) * 8;
  const float* src = x + ((size_t)b * kT + T) * kDIN + k0;
  u16* dst = d + ((size_t)fg) * 512 + lane * 8;
#pragma unroll
  for (int i = 0; i < 8; i++) dst[i] = f2bf(src[i]);
}

// ---------------------------------------------------------------------------
// Chunk-decoupled fused recurrence — r10 structure (verified) with ONE
// change: LDS-DEDUP of the coherent A-frag exchange loads.
//
// Model (fits r0/r3/r5/r10 data): the exchange is LLC-BANDWIDTH-bound at
// ~4-4.5 TB/s effective. Wave pairs (same mt) used to fetch IDENTICAL 16 KB
// regions from the LLC (64 KB/block/step coherent). Now each wave loads
// only its 8-fragment HALF (kt = u*8..u*8+7), stages to a 32 KB LDS strip,
// one __syncthreads, then all waves ds_read all 16 fragments. Coherent
// bytes/step halve: 16 MB -> 8 MB across the chip.
// Ordering: asm loads -> [cover MFMAs] -> vmcnt(0) ("memory" orders the
// following ds_writes, which are memory ops — rule-18-safe) -> ds_write ->
// __syncthreads -> ds_read. WAR on the strip: two barriers separate step
// t's ds_reads from step t+1's ds_writes. Flag barrier, publishes, targets:
// byte-identical to r10 (verified).
// ---------------------------------------------------------------------------
__global__ __launch_bounds__(256, 1)
void rec_fused(int c, int TC, int nc, unsigned* bar,
               const u16* __restrict__ xpl,
               const u16* __restrict__ slab0hh, const u16* __restrict__ slab0ih,
               const u16* __restrict__ slab1hh, const u16* __restrict__ slab1ih,
               const float* __restrict__ bih0, const float* __restrict__ bhh0,
               const float* __restrict__ bih1, const float* __restrict__ bhh1,
               u16* __restrict__ h1pl, u16* __restrict__ hbuf,
               float* __restrict__ carry) {
  __shared__ u16 ldsw[96 * 512];     // layer1: w_ih1 jt-slice (96 KB)
  __shared__ u16 stage[2 * 8192];    // A-frag staging strip (32 KB)

  const int bid   = blockIdx.x;
  const int layer = bid >> 7;
  const int lb    = bid & 127;
  const int jt    = lb & 15, bt = lb >> 4;
  const int gid   = layer * 8 + bt;
  const int cc    = (layer == 0) ? c : c - 1;
  const bool active = (cc >= 0 && cc < nc);

  // per-group flag array: 16 flags, 64 B apart (single writer each)
  unsigned* flags  = bar + (size_t)gid * 16 * 16;
  unsigned* myflag = flags + (size_t)jt * 16;
  const unsigned tagbase = (unsigned)c * (unsigned)TC;

  if (!active) {   // whole (layer,bt) group inactive together: fast-forward
    if (threadIdx.x == 0)
      __hip_atomic_store(myflag, tagbase + (unsigned)TC, __ATOMIC_RELAXED,
                         __HIP_MEMORY_SCOPE_AGENT);
    return;
  }

  const int tid   = threadIdx.x;
  const int wv    = tid >> 6, lane = tid & 63;
  const int mt    = wv >> 1, u = wv & 1;
  const int jl    = lane & 15;
  const int jg    = jt * 32 + u * 16 + jl;
  const int mrow  = (lane >> 4) * 4;
  const int bbase = bt * 32 + mt * 16 + mrow;

  // coherent-load half-region base (this wave's 8 kt), and LDS strip bases
  const size_t reg_off  = ((size_t)((bt * 2 + mt) * 16) + (size_t)u * 8) * 512
                        + (size_t)lane * 8;
  u16* stg_w = stage + (size_t)mt * 8192 + (size_t)u * 8 * 512 + (size_t)lane * 8;
  const u16* stg_r = stage + (size_t)mt * 8192 + (size_t)lane * 8;

  const size_t prod_off = ((size_t)((bt * 2 + mt) * 16 + jt)) * 512 +
                          (size_t)(16 * (u * 2 + (jl >> 3))) * 8 + (jl & 7);
  float* mycarry = carry + (size_t)layer * kB * kH;

  // wave-0 parallel flag poll (lane L watches flag[L&15]); then block release
  auto block_wait = [&](unsigned tgt) {
    if (wv == 0) {
      unsigned* fp = flags + (size_t)(lane & 15) * 16;
      int guard = 0;
      while (__hip_atomic_load(fp, __ATOMIC_RELAXED,
                               __HIP_MEMORY_SCOPE_AGENT) < tgt &&
             ++guard < (1 << 21))
        __builtin_amdgcn_s_sleep(1);
    }
    __syncthreads();
  };

  if (layer == 0) {
    // ---- resident: w_hh0 (48 frags) + w_ih0 (6 frags) ----
    s8v bh[3][16];
    {
      const u16* base = slab0hh + (size_t)jt * 96 * 512 + (size_t)lane * 8;
#pragma unroll
      for (int g = 0; g < 3; ++g)
#pragma unroll
        for (int kt = 0; kt < 16; ++kt)
          bh[g][kt] = *(const s8v*)(base + (size_t)((g * 2 + u) * 16 + kt) * 512);
    }
    s8v bx[3][2];
    {
      const u16* base = slab0ih + (size_t)jt * 12 * 512 + (size_t)lane * 8;
#pragma unroll
      for (int g = 0; g < 3; ++g)
#pragma unroll
        for (int kt = 0; kt < 2; ++kt)
          bx[g][kt] = *(const s8v*)(base + (size_t)((g * 2 + u) * 2 + kt) * 512);
    }
    const float br  = bih0[jg] + bhh0[jg];
    const float bz  = bih0[512 + jg] + bhh0[512 + jg];
    const float bni = bih0[1024 + jg], bnh = bhh0[1024 + jg];

    float hp[4];
#pragma unroll
    for (int r = 0; r < 4; ++r)
      hp[r] = mycarry[(size_t)(bbase + r) * 512 + jg];

    const size_t xoff = (size_t)((bt * 2 + mt) * 2) * 512 + (size_t)lane * 8;
    const u16* xb0 = xpl + (size_t)(cc * TC) * kXStep + xoff;
    s8v ax0 = *(const s8v*)xb0;
    s8v ax1 = *(const s8v*)(xb0 + 512);

    for (int t = 0; t < TC; ++t) {
      block_wait(tagbase + (unsigned)t);

      // this wave's HALF of h1_{t-1} (8 frags, coherent); x MFMAs cover it
      i4v s[8];
      load8_nw(hbuf + (size_t)(t & 1) * kPlane + reg_off, s);

      const f4v z4 = {0.f, 0.f, 0.f, 0.f};
      f4v acc0, acc1, acc2, acc2x;
      acc0  = MFMA16(ax0, bx[0][0], z4, 0, 0, 0);
      acc0  = MFMA16(ax1, bx[0][1], acc0, 0, 0, 0);
      acc1  = MFMA16(ax0, bx[1][0], z4, 0, 0, 0);
      acc1  = MFMA16(ax1, bx[1][1], acc1, 0, 0, 0);
      acc2x = MFMA16(ax0, bx[2][0], z4, 0, 0, 0);
      acc2x = MFMA16(ax1, bx[2][1], acc2x, 0, 0, 0);
      acc2  = z4;
      asm volatile("s_waitcnt vmcnt(0)" ::: "memory");   // halves landed
      // stage to LDS, share across the mt wave pair
#pragma unroll
      for (int i = 0; i < 8; ++i)
        *(i4v*)(stg_w + (size_t)i * 512) = s[i];
      __syncthreads();

#pragma unroll
      for (int kt = 0; kt < 16; ++kt) {
        const s8v av = *(const s8v*)(stg_r + (size_t)kt * 512);
        acc0 = MFMA16(av, bh[0][kt], acc0, 0, 0, 0);
        acc1 = MFMA16(av, bh[1][kt], acc1, 0, 0, 0);
        acc2 = MFMA16(av, bh[2][kt], acc2, 0, 0, 0);
      }

      unsigned hv[4];
#pragma unroll
      for (int r = 0; r < 4; ++r) {
        float rr = fsig(acc0[r] + br);
        float zz = fsig(acc1[r] + bz);
        float nn = ftanh(acc2x[r] + bni + rr * (acc2[r] + bnh));
        float hn = (1.f - zz) * nn + zz * hp[r];
        hp[r] = hn;
        hv[r] = f2bf(hn);
      }

      // publish h1_t: hbuf (group exchange, coherent) + h1pl (next dispatch)
      u16* pb = hbuf + (size_t)((t + 1) & 1) * kPlane + prod_off;
      u16* qb = h1pl + (size_t)((cc & 1) * TC + t) * kPlane + prod_off;
      store_h_l0(pb + (size_t)(mrow + 0) * 8, pb + (size_t)(mrow + 1) * 8,
                 pb + (size_t)(mrow + 2) * 8, pb + (size_t)(mrow + 3) * 8,
                 qb + (size_t)(mrow + 0) * 8, qb + (size_t)(mrow + 1) * 8,
                 qb + (size_t)(mrow + 2) * 8, qb + (size_t)(mrow + 3) * 8,
                 hv[0], hv[1], hv[2], hv[3]);
      __syncthreads();                 // all waves' publishes drained
      if (tid == 0)
        __hip_atomic_store(myflag, tagbase + (unsigned)(t + 1),
                           __ATOMIC_RELAXED, __HIP_MEMORY_SCOPE_AGENT);
      if (t + 1 < TC) {   // x frags for t+1 fly during next wait phase
        const u16* xb = xpl + (size_t)(cc * TC + t + 1) * kXStep + xoff;
        ax0 = *(const s8v*)xb;
        ax1 = *(const s8v*)(xb + 512);
      }
    }
#pragma unroll
    for (int r = 0; r < 4; ++r)
      mycarry[(size_t)(bbase + r) * 512 + jg] = hp[r];
  } else {
    // ---- w_ih1 jt-slice -> LDS (once); w_hh1 resident in VGPRs ----
    {
      const u16* src = slab1ih + (size_t)jt * 96 * 512;
      for (int i = tid; i < 96 * 512 / 8; i += 256)
        *(s8v*)&ldsw[i * 8] = *(const s8v*)&src[i * 8];
    }
    s8v bh[3][16];
    {
      const u16* base = slab1hh + (size_t)jt * 96 * 512 + (size_t)lane * 8;
#pragma unroll
      for (int g = 0; g < 3; ++g)
#pragma unroll
        for (int kt = 0; kt < 16; ++kt)
          bh[g][kt] = *(const s8v*)(base + (size_t)((g * 2 + u) * 16 + kt) * 512);
    }
    const float br  = bih1[jg] + bhh1[jg];
    const float bz  = bih1[512 + jg] + bhh1[512 + jg];
    const float bni = bih1[1024 + jg], bnh = bhh1[1024 + jg];

    float hp[4];
#pragma unroll
    for (int r = 0; r < 4; ++r)
      hp[r] = mycarry[(size_t)(bbase + r) * 512 + jg];

    // h1 A-frag source for chunk cc (stable data, plain-cached)
    const u16* h1base = h1pl + (size_t)((cc & 1) * TC) * kPlane +
                        ((size_t)((bt * 2 + mt) * 16)) * 512 + (size_t)lane * 8;
    s8v a1[16];
#pragma unroll
    for (int kt = 0; kt < 16; ++kt)
      a1[kt] = *(const s8v*)(h1base + (size_t)kt * 512);

    for (int t = 0; t < TC; ++t) {
      block_wait(tagbase + (unsigned)t);   // also orders the LDS fill (t=0)

      // this wave's HALF of h2_{t-1} (8 frags, coherent); ih MFMAs cover it
      i4v s[8];
      load8_nw(hbuf + (size_t)(2 + (t & 1)) * kPlane + reg_off, s);

      const f4v z4 = {0.f, 0.f, 0.f, 0.f};
      f4v acc0 = z4, acc1 = z4, acc2 = z4, acc2x = z4;
#pragma unroll
      for (int kt = 0; kt < 16; ++kt) {
        const s8v b0 = *(const s8v*)&ldsw[(size_t)((0 + u) * 16 + kt) * 512 + lane * 8];
        const s8v b1 = *(const s8v*)&ldsw[(size_t)((2 + u) * 16 + kt) * 512 + lane * 8];
        const s8v b2 = *(const s8v*)&ldsw[(size_t)((4 + u) * 16 + kt) * 512 + lane * 8];
        acc0  = MFMA16(a1[kt], b0, acc0, 0, 0, 0);
        acc1  = MFMA16(a1[kt], b1, acc1, 0, 0, 0);
        acc2x = MFMA16(a1[kt], b2, acc2x, 0, 0, 0);
      }
      asm volatile("s_waitcnt vmcnt(0)" ::: "memory");   // halves landed
#pragma unroll
      for (int i = 0; i < 8; ++i)
        *(i4v*)(stg_w + (size_t)i * 512) = s[i];
      __syncthreads();

#pragma unroll
      for (int kt = 0; kt < 16; ++kt) {
        const s8v av = *(const s8v*)(stg_r + (size_t)kt * 512);
        acc0 = MFMA16(av, bh[0][kt], acc0, 0, 0, 0);
        acc1 = MFMA16(av, bh[1][kt], acc1, 0, 0, 0);
        acc2 = MFMA16(av, bh[2][kt], acc2, 0, 0, 0);
      }

      unsigned hv[4];
#pragma unroll
      for (int r = 0; r < 4; ++r) {
        float rr = fsig(acc0[r] + br);
        float zz = fsig(acc1[r] + bz);
        float nn = ftanh(acc2x[r] + bni + rr * (acc2[r] + bnh));
        float hn = (1.f - zz) * nn + zz * hp[r];
        hp[r] = hn;
        hv[r] = f2bf(hn);
      }

      u16* pb = hbuf + (size_t)(2 + ((t + 1) & 1)) * kPlane + prod_off;
      store_h_l1(pb + (size_t)(mrow + 0) * 8, pb + (size_t)(mrow + 1) * 8,
                 pb + (size_t)(mrow + 2) * 8, pb + (size_t)(mrow + 3) * 8,
                 hv[0], hv[1], hv[2], hv[3]);
      __syncthreads();                 // all waves' publishes drained
      if (tid == 0)
        __hip_atomic_store(myflag, tagbase + (unsigned)(t + 1),
                           __ATOMIC_RELAXED, __HIP_MEMORY_SCOPE_AGENT);
      if (t + 1 < TC) {   // h1 frags for t+1 fly during next wait phase
        const u16* hb = h1base + (size_t)(t + 1) * kPlane;
#pragma unroll
        for (int kt = 0; kt < 16; ++kt)
          a1[kt] = *(const s8v*)(hb + (size_t)kt * 512);
      }
    }
#pragma unroll
    for (int r = 0; r < 4; ++r)
      mycarry[(size_t)(bbase + r) * 512 + jg] = hp[r];
  }
}

// ---------------------------------------------------------------------------
__global__ __launch_bounds__(128)
void fc_kernel(const float* __restrict__ h, const float* __restrict__ wfc,
               const float* __restrict__ bfc, float* __restrict__ out) {
  const int b = blockIdx.x;
  const int n = threadIdx.x;
  const float* hrow = h + (size_t)b * kH;
  const float* wrow = wfc + (size_t)n * kH;
  float acc = 0.f;
#pragma unroll 4
  for (int k = 0; k < kH; k += 4) {
    const float4 hv = *(const float4*)&hrow[k];
    const float4 wv = *(const float4*)&wrow[k];
    acc = fmaf(hv.x, wv.x, acc); acc = fmaf(hv.y, wv.y, acc);
    acc = fmaf(hv.z, wv.z, acc); acc = fmaf(hv.w, wv.w, acc);
  }
  out[(size_t)b * kNOUT + n] = acc + bfc[n];
}

// ---------------------------------------------------------------------------
extern "C" void kernel_launch(void* const* d_in, const int* in_sizes, int n_in,
                              void* d_out, int out_size, void* d_ws, size_t ws_size,
                              hipStream_t stream) {
  const float* x     = (const float*)d_in[0];
  const float* w_ih0 = (const float*)d_in[1];
  const float* w_hh0 = (const float*)d_in[2];
  const float* b_ih0 = (const float*)d_in[3];
  const float* b_hh0 = (const float*)d_in[4];
  const float* w_ih1 = (const float*)d_in[5];
  const float* w_hh1 = (const float*)d_in[6];
  const float* b_ih1 = (const float*)d_in[7];
  const float* b_hh1 = (const float*)d_in[8];
  const float* w_fc  = (const float*)d_in[9];
  const float* b_fc  = (const float*)d_in[10];
  float* out = (float*)d_out;

  // workspace: slabs 4.7 MB + xpl 16.8 MB + h1pl 2*TC*256KB + hbuf 1 MB +
  // carry 1 MB + flags 16 KB.  TC=64 -> ~57 MB total.
  auto need = [](int tc) -> size_t {
    size_t s = 0;
    s += 3 * (size_t)kG3 * kH * 2;        // slab0hh, slab1hh, slab1ih
    s += (size_t)kG3 * kDIN * 2;          // slab0ih
    s += (size_t)kT * kXStep * 2;         // xpl
    s += 2 * (size_t)tc * kPlane * 2;     // h1pl (chunk-parity dbuf)
    s += 4 * (size_t)kPlane * 2;          // hbuf
    s += 2 * (size_t)kB * kH * 4;         // carry
    s += 131072;
    return s;
  };
  int TC = 64;
  while (TC > 2 && need(TC) > ws_size) TC >>= 1;
  const int nc = kT / TC;

  char* p = (char*)d_ws;
  auto carve = [&](size_t bytes) {
    char* r = p; p += (bytes + 255) & ~(size_t)255; return r;
  };
  u16* slab0hh = (u16*)carve((size_t)kG3 * kH * 2);
  u16* slab1hh = (u16*)carve((size_t)kG3 * kH * 2);
  u16* slab1ih = (u16*)carve((size_t)kG3 * kH * 2);
  u16* slab0ih = (u16*)carve((size_t)kG3 * kDIN * 2);
  u16* xpl     = (u16*)carve((size_t)kT * kXStep * 2);
  u16* h1pl    = (u16*)carve(2 * (size_t)TC * kPlane * 2);
  u16* hbuf    = (u16*)carve(4 * (size_t)kPlane * 2);
  float* carry = (float*)carve(2 * (size_t)kB * kH * 4);
  unsigned* bar = (unsigned*)carve(16 * 16 * 16 * sizeof(unsigned)); // flags

  // prologue: swizzles + zero h planes/carries + flag words
  build_wslab<<<384, 256, 0, stream>>>(w_hh0, slab0hh);
  build_wslab<<<384, 256, 0, stream>>>(w_hh1, slab1hh);
  build_wslab<<<384, 256, 0, stream>>>(w_ih1, slab1ih);
  build_wslab_ih0<<<48, 256, 0, stream>>>(w_ih0, slab0ih);
  build_xplane<<<4096, 256, 0, stream>>>(x, xpl);
  hipMemsetAsync(hbuf, 0, 4 * (size_t)kPlane * 2 + 2 * (size_t)kB * kH * 4, stream);
  hipMemsetAsync(bar, 0, 16 * 16 * 16 * sizeof(unsigned), stream);

  // pipeline: dispatch c runs rec0(c) + rec1(c-1); no serial GEMMs.
  for (int c = 0; c <= nc; ++c) {
    rec_fused<<<dim3(256), dim3(256), 0, stream>>>(
        c, TC, nc, bar, xpl,
        slab0hh, slab0ih, slab1hh, slab1ih,
        b_ih0, b_hh0, b_ih1, b_hh1,
        h1pl, hbuf, carry);
  }

  // final FC on layer-1 terminal state
  fc_kernel<<<dim3(kB), dim3(kNOUT), 0, stream>>>(
      carry + (size_t)kB * kH, w_fc, b_fc, out);
}

// Round 12
// 2321.405 us; speedup vs baseline: 1.0720x; 1.0720x over previous
//
#include <hip/hip_runtime.h>
#include <math.h>

typedef unsigned short u16;
typedef __attribute__((ext_vector_type(8))) short s8v;   // 8 x bf16 (4 VGPRs)
typedef __attribute__((ext_vector_type(4))) float f4v;   // MFMA accumulator
typedef __attribute__((ext_vector_type(4))) int   i4v;   // asm load payload

constexpr int kB    = 256;
constexpr int kT    = 512;
constexpr int kDIN  = 64;
constexpr int kH    = 512;
constexpr int kG3   = 1536;
constexpr int kNOUT = 128;
constexpr int kPlane = 8 * 2 * 16 * 512;   // u16 per h A-frag plane (131072)
constexpr int kXStep = 16 * 2 * 512;       // u16 per x A-frag step (16384)

#define MFMA16 __builtin_amdgcn_mfma_f32_16x16x32_bf16

__device__ __forceinline__ u16 f2bf(float f) {   // round-to-nearest-even
  union { float f; unsigned u; } v; v.f = f;
  unsigned r = (v.u + 0x7FFFu + ((v.u >> 16) & 1u)) >> 16;
  return (u16)r;
}
__device__ __forceinline__ float fsig(float x) {
  x = fminf(fmaxf(x, -30.f), 30.f);
  float e = __expf(-x);
  return __fdividef(1.f, 1.f + e);
}
__device__ __forceinline__ float ftanh(float x) {
  x = fminf(fmaxf(x, -15.f), 15.f);
  float e = __expf(-2.f * x);
  return __fdividef(1.f - e, 1.f + e);
}

// 16 A-fragment loads (16 B/lane, kt stride 1024 B), LLC-coherent bypass,
// NO trailing wait — caller places compute between issue and vmcnt(0).
__device__ __forceinline__ void load16_nw(const u16* base, i4v a[16]) {
  asm volatile(
      "global_load_dwordx4 %0, %16, off sc0 sc1\n\t"
      "global_load_dwordx4 %1, %16, off offset:1024 sc0 sc1\n\t"
      "global_load_dwordx4 %2, %16, off offset:2048 sc0 sc1\n\t"
      "global_load_dwordx4 %3, %16, off offset:3072 sc0 sc1\n\t"
      "global_load_dwordx4 %4, %17, off sc0 sc1\n\t"
      "global_load_dwordx4 %5, %17, off offset:1024 sc0 sc1\n\t"
      "global_load_dwordx4 %6, %17, off offset:2048 sc0 sc1\n\t"
      "global_load_dwordx4 %7, %17, off offset:3072 sc0 sc1\n\t"
      "global_load_dwordx4 %8, %18, off sc0 sc1\n\t"
      "global_load_dwordx4 %9, %18, off offset:1024 sc0 sc1\n\t"
      "global_load_dwordx4 %10, %18, off offset:2048 sc0 sc1\n\t"
      "global_load_dwordx4 %11, %18, off offset:3072 sc0 sc1\n\t"
      "global_load_dwordx4 %12, %19, off sc0 sc1\n\t"
      "global_load_dwordx4 %13, %19, off offset:1024 sc0 sc1\n\t"
      "global_load_dwordx4 %14, %19, off offset:2048 sc0 sc1\n\t"
      "global_load_dwordx4 %15, %19, off offset:3072 sc0 sc1"
      : "=&v"(a[0]), "=&v"(a[1]), "=&v"(a[2]), "=&v"(a[3]),
        "=&v"(a[4]), "=&v"(a[5]), "=&v"(a[6]), "=&v"(a[7]),
        "=&v"(a[8]), "=&v"(a[9]), "=&v"(a[10]), "=&v"(a[11]),
        "=&v"(a[12]), "=&v"(a[13]), "=&v"(a[14]), "=&v"(a[15])
      : "v"(base), "v"(base + 4 * 512), "v"(base + 8 * 512), "v"(base + 12 * 512)
      : "memory");
}

// Layer-0 publish: 4 coherent hbuf stores FIRST, then 4 plain h1pl stores,
// then vmcnt(4) — waits only the hbuf 4; h1pl drains during the barrier
// round (vmcnt retires in issue order). (Verified round-0/5 pattern.)
__device__ __forceinline__ void store_h_l0(
    u16* p0, u16* p1, u16* p2, u16* p3,
    u16* q0, u16* q1, u16* q2, u16* q3,
    unsigned v0, unsigned v1, unsigned v2, unsigned v3) {
  asm volatile(
      "global_store_short %0, %8, off sc0 sc1\n\t"
      "global_store_short %1, %9, off sc0 sc1\n\t"
      "global_store_short %2, %10, off sc0 sc1\n\t"
      "global_store_short %3, %11, off sc0 sc1\n\t"
      "global_store_short %4, %8, off\n\t"
      "global_store_short %5, %9, off\n\t"
      "global_store_short %6, %10, off\n\t"
      "global_store_short %7, %11, off\n\t"
      "s_waitcnt vmcnt(4)"
      :: "v"(p0), "v"(p1), "v"(p2), "v"(p3),
         "v"(q0), "v"(q1), "v"(q2), "v"(q3),
         "v"(v0), "v"(v1), "v"(v2), "v"(v3)
      : "memory");
}
// Layer-1: 4 coherent stores + full drain. (Verified round-0/5.)
__device__ __forceinline__ void store_h_l1(
    u16* p0, u16* p1, u16* p2, u16* p3,
    unsigned v0, unsigned v1, unsigned v2, unsigned v3) {
  asm volatile(
      "global_store_short %0, %4, off sc0 sc1\n\t"
      "global_store_short %1, %5, off sc0 sc1\n\t"
      "global_store_short %2, %6, off sc0 sc1\n\t"
      "global_store_short %3, %7, off sc0 sc1\n\t"
      "s_waitcnt vmcnt(0)"
      :: "v"(p0), "v"(p1), "v"(p2), "v"(p3),
         "v"(v0), "v"(v1), "v"(v2), "v"(v3)
      : "memory");
}

// ---------------------------------------------------------------------------
// B-frag slab for [1536][512] fp32 weights (w_hh0, w_hh1, w_ih1).
// Layout: [jt 16][f 96][lane 64][8], f = (g*2+u)*16 + kt.   (Verified r0-r5.)
// ---------------------------------------------------------------------------
__global__ void build_wslab(const float* __restrict__ w, u16* __restrict__ d) {
  int idx  = blockIdx.x * 256 + threadIdx.x;   // 0..98303
  int lane = idx & 63, fg = idx >> 6;          // fg = jt*96 + f
  int jt = fg / 96, f = fg % 96;
  int nt = f >> 4, kt = f & 15;
  int g = nt >> 1, u = nt & 1;
  int row = g * 512 + jt * 32 + u * 16 + (lane & 15);
  int k0  = kt * 32 + (lane >> 4) * 8;
  const float* src = w + (size_t)row * 512 + k0;
  u16* dst = d + ((size_t)fg) * 512 + lane * 8;
#pragma unroll
  for (int i = 0; i < 8; i++) dst[i] = f2bf(src[i]);
}

// B-frag slab for w_ih0 [1536][64]: [jt 16][f 12][lane 64][8], f=(g*2+u)*2+kt.
// (Verified round-4/5.)
__global__ void build_wslab_ih0(const float* __restrict__ w, u16* __restrict__ d) {
  int idx  = blockIdx.x * 256 + threadIdx.x;   // 0..12287
  int lane = idx & 63, fg = idx >> 6;          // fg = jt*12 + f
  int jt = fg / 12, f = fg % 12;
  int nt = f >> 1, kt = f & 1;
  int g = nt >> 1, u = nt & 1;
  int row = g * 512 + jt * 32 + u * 16 + (lane & 15);
  int k0  = kt * 32 + (lane >> 4) * 8;
  const float* src = w + (size_t)row * kDIN + k0;
  u16* dst = d + ((size_t)fg) * 512 + lane * 8;
#pragma unroll
  for (int i = 0; i < 8; i++) dst[i] = f2bf(src[i]);
}

// x [256][512][64] fp32 -> per-step A-frag planes (bf16). (Verified r4/r5.)
__global__ void build_xplane(const float* __restrict__ x, u16* __restrict__ d) {
  int idx  = blockIdx.x * 256 + threadIdx.x;   // 0..1048575
  int lane = idx & 63, fg = idx >> 6;          // fg = (T*16+m)*2+kt
  int kt = fg & 1, m = (fg >> 1) & 15, T = fg >> 5;
  int b  = m * 16 + (lane & 15);
  int k0 = kt * 32 + (lane >> 4) * 8;
  const float* src = x + ((size_t)b * kT + T) * kDIN + k0;
  u16* dst = d + ((size_t)fg) * 512 + lane * 8;
#pragma unroll
  for (int i = 0; i < 8; i++) dst[i] = f2bf(src[i]);
}

// ---------------------------------------------------------------------------
// Chunk-decoupled fused recurrence (VERIFIED round-5 configuration — the
// measured best of this design: steady 267 us/dispatch, total 2333 us).
// Blocks 0..127: layer0 chunk c (fused proj0 via xplane). Blocks 128..255:
// layer1 chunk c-1 (fused proj1: h1pl A-frags + w_ih1 from LDS).
// Barrier protocol = verified round-0: per-(layer,bt) 16-block groups,
// tid0 LLC poll -> __syncthreads -> coherent loads/stores -> drain ->
// __syncthreads -> relaxed agent arrive. Layer1's h1 input (h1pl, chunk
// c-1) is STABLE data written in the previous dispatch -> zero step-level
// cross-layer coupling. Its per-step ih work (16 frag prefetch + 48
// LDS-fed MFMAs) hides in the barrier-wait + h2-load shadow.
//
// Design-space closure (r7-r11 measured): schedule placement, sync
// mechanism (flags vs atomics), sync granularity (per-wave), and coherent
// bandwidth (LDS-dedup) are ALL neutral-to-negative on this slot — the
// step time is the closed-loop communication chain (publish-drain -> LLC
// visibility -> detect -> coherent reload) with compute fully hidden.
// This configuration is the empirical floor of the topology.
// ---------------------------------------------------------------------------
__global__ __launch_bounds__(256, 1)
void rec_fused(int c, int TC, int nc, unsigned bar_base16, unsigned* bar,
               const u16* __restrict__ xpl,
               const u16* __restrict__ slab0hh, const u16* __restrict__ slab0ih,
               const u16* __restrict__ slab1hh, const u16* __restrict__ slab1ih,
               const float* __restrict__ bih0, const float* __restrict__ bhh0,
               const float* __restrict__ bih1, const float* __restrict__ bhh1,
               u16* __restrict__ h1pl, u16* __restrict__ hbuf,
               float* __restrict__ carry) {
  __shared__ u16 ldsw[96 * 512];   // layer1: w_ih1 jt-slice (96 KB)

  const int bid   = blockIdx.x;
  const int layer = bid >> 7;
  const int lb    = bid & 127;
  const int jt    = lb & 15, bt = lb >> 4;
  const int cc    = (layer == 0) ? c : c - 1;
  const bool active = (cc >= 0 && cc < nc);

  unsigned* mybar = bar + (size_t)(layer * 8 + bt) * 64;   // own cacheline

  if (!active) {   // whole (layer,bt) group inactive together: fast-forward
    if (threadIdx.x == 0)
      __hip_atomic_fetch_add(mybar, (unsigned)TC, __ATOMIC_RELAXED,
                             __HIP_MEMORY_SCOPE_AGENT);
    return;
  }

  const int tid   = threadIdx.x;
  const int wv    = tid >> 6, lane = tid & 63;
  const int mt    = wv >> 1, u = wv & 1;
  const int jl    = lane & 15;
  const int jg    = jt * 32 + u * 16 + jl;
  const int mrow  = (lane >> 4) * 4;
  const int bbase = bt * 32 + mt * 16 + mrow;

  const size_t cons_off = ((size_t)((bt * 2 + mt) * 16)) * 512 + lane * 8;
  const size_t prod_off = ((size_t)((bt * 2 + mt) * 16 + jt)) * 512 +
                          (size_t)(16 * (u * 2 + (jl >> 3))) * 8 + (jl & 7);
  float* mycarry = carry + (size_t)layer * kB * kH;

  if (layer == 0) {
    // ---- resident: w_hh0 (48 frags) + w_ih0 (6 frags) ----
    s8v bh[3][16];
    {
      const u16* base = slab0hh + (size_t)jt * 96 * 512 + (size_t)lane * 8;
#pragma unroll
      for (int g = 0; g < 3; ++g)
#pragma unroll
        for (int kt = 0; kt < 16; ++kt)
          bh[g][kt] = *(const s8v*)(base + (size_t)((g * 2 + u) * 16 + kt) * 512);
    }
    s8v bx[3][2];
    {
      const u16* base = slab0ih + (size_t)jt * 12 * 512 + (size_t)lane * 8;
#pragma unroll
      for (int g = 0; g < 3; ++g)
#pragma unroll
        for (int kt = 0; kt < 2; ++kt)
          bx[g][kt] = *(const s8v*)(base + (size_t)((g * 2 + u) * 2 + kt) * 512);
    }
    const float br  = bih0[jg] + bhh0[jg];
    const float bz  = bih0[512 + jg] + bhh0[512 + jg];
    const float bni = bih0[1024 + jg], bnh = bhh0[1024 + jg];

    float hp[4];
#pragma unroll
    for (int r = 0; r < 4; ++r)
      hp[r] = mycarry[(size_t)(bbase + r) * 512 + jg];

    const size_t xoff = (size_t)((bt * 2 + mt) * 2) * 512 + (size_t)lane * 8;
    const u16* xb0 = xpl + (size_t)(cc * TC) * kXStep + xoff;
    s8v ax0 = *(const s8v*)xb0;
    s8v ax1 = *(const s8v*)(xb0 + 512);

    for (int t = 0; t < TC; ++t) {
      if (tid == 0) {
        unsigned tgt = bar_base16 + 16u * (unsigned)t;
        int guard = 0;
        while (__hip_atomic_load(mybar, __ATOMIC_RELAXED,
                                 __HIP_MEMORY_SCOPE_AGENT) < tgt
               && ++guard < (1 << 21))
          __builtin_amdgcn_s_sleep(1);
      }
      __syncthreads();

      // issue h1_{t-1} loads; x MFMAs run under the LLC latency
      i4v a[16];
      load16_nw(hbuf + (size_t)(t & 1) * kPlane + cons_off, a);

      const f4v z4 = {0.f, 0.f, 0.f, 0.f};
      f4v acc0, acc1, acc2, acc2x;
      acc0  = MFMA16(ax0, bx[0][0], z4, 0, 0, 0);
      acc0  = MFMA16(ax1, bx[0][1], acc0, 0, 0, 0);
      acc1  = MFMA16(ax0, bx[1][0], z4, 0, 0, 0);
      acc1  = MFMA16(ax1, bx[1][1], acc1, 0, 0, 0);
      acc2x = MFMA16(ax0, bx[2][0], z4, 0, 0, 0);
      acc2x = MFMA16(ax1, bx[2][1], acc2x, 0, 0, 0);
      acc2  = z4;
      asm volatile("s_waitcnt vmcnt(0)" ::: "memory");
      __builtin_amdgcn_sched_barrier(0);   // rule #18: pin hh MFMAs below
#pragma unroll
      for (int kt = 0; kt < 16; ++kt) {
        const s8v av = __builtin_bit_cast(s8v, a[kt]);
        acc0 = MFMA16(av, bh[0][kt], acc0, 0, 0, 0);
        acc1 = MFMA16(av, bh[1][kt], acc1, 0, 0, 0);
        acc2 = MFMA16(av, bh[2][kt], acc2, 0, 0, 0);
      }

      unsigned hv[4];
#pragma unroll
      for (int r = 0; r < 4; ++r) {
        float rr = fsig(acc0[r] + br);
        float zz = fsig(acc1[r] + bz);
        float nn = ftanh(acc2x[r] + bni + rr * (acc2[r] + bnh));
        float hn = (1.f - zz) * nn + zz * hp[r];
        hp[r] = hn;
        hv[r] = f2bf(hn);
      }

      // publish h1_t: hbuf (group exchange, coherent) + h1pl (next dispatch)
      u16* pb = hbuf + (size_t)((t + 1) & 1) * kPlane + prod_off;
      u16* qb = h1pl + (size_t)((cc & 1) * TC + t) * kPlane + prod_off;
      store_h_l0(pb + (size_t)(mrow + 0) * 8, pb + (size_t)(mrow + 1) * 8,
                 pb + (size_t)(mrow + 2) * 8, pb + (size_t)(mrow + 3) * 8,
                 qb + (size_t)(mrow + 0) * 8, qb + (size_t)(mrow + 1) * 8,
                 qb + (size_t)(mrow + 2) * 8, qb + (size_t)(mrow + 3) * 8,
                 hv[0], hv[1], hv[2], hv[3]);
      __syncthreads();
      if (tid == 0)
        __hip_atomic_fetch_add(mybar, 1u, __ATOMIC_RELAXED,
                               __HIP_MEMORY_SCOPE_AGENT);
      if (t + 1 < TC) {   // x frags for t+1 fly during next wait phase
        const u16* xb = xpl + (size_t)(cc * TC + t + 1) * kXStep + xoff;
        ax0 = *(const s8v*)xb;
        ax1 = *(const s8v*)(xb + 512);
      }
    }
#pragma unroll
    for (int r = 0; r < 4; ++r)
      mycarry[(size_t)(bbase + r) * 512 + jg] = hp[r];
  } else {
    // ---- w_ih1 jt-slice -> LDS (once); w_hh1 resident in VGPRs ----
    {
      const u16* src = slab1ih + (size_t)jt * 96 * 512;
      for (int i = tid; i < 96 * 512 / 8; i += 256)
        *(s8v*)&ldsw[i * 8] = *(const s8v*)&src[i * 8];
    }
    s8v bh[3][16];
    {
      const u16* base = slab1hh + (size_t)jt * 96 * 512 + (size_t)lane * 8;
#pragma unroll
      for (int g = 0; g < 3; ++g)
#pragma unroll
        for (int kt = 0; kt < 16; ++kt)
          bh[g][kt] = *(const s8v*)(base + (size_t)((g * 2 + u) * 16 + kt) * 512);
    }
    const float br  = bih1[jg] + bhh1[jg];
    const float bz  = bih1[512 + jg] + bhh1[512 + jg];
    const float bni = bih1[1024 + jg], bnh = bhh1[1024 + jg];

    float hp[4];
#pragma unroll
    for (int r = 0; r < 4; ++r)
      hp[r] = mycarry[(size_t)(bbase + r) * 512 + jg];

    // h1 A-frag source for chunk cc (stable data from previous dispatch)
    const u16* h1base = h1pl + (size_t)((cc & 1) * TC) * kPlane + cons_off;
    s8v a1[16];
#pragma unroll
    for (int kt = 0; kt < 16; ++kt)
      a1[kt] = *(const s8v*)(h1base + (size_t)kt * 512);

    for (int t = 0; t < TC; ++t) {
      if (tid == 0) {
        unsigned tgt = bar_base16 + 16u * (unsigned)t;
        int guard = 0;
        while (__hip_atomic_load(mybar, __ATOMIC_RELAXED,
                                 __HIP_MEMORY_SCOPE_AGENT) < tgt
               && ++guard < (1 << 21))
          __builtin_amdgcn_s_sleep(1);
      }
      __syncthreads();   // also orders the LDS fill before first ds_read

      // issue h2_{t-1} loads; ih MFMAs (a1 + LDS weights) run underneath
      i4v a2[16];
      load16_nw(hbuf + (size_t)(2 + (t & 1)) * kPlane + cons_off, a2);

      const f4v z4 = {0.f, 0.f, 0.f, 0.f};
      f4v acc0 = z4, acc1 = z4, acc2 = z4, acc2x = z4;
#pragma unroll
      for (int kt = 0; kt < 16; ++kt) {
        const s8v b0 = *(const s8v*)&ldsw[(size_t)((0 + u) * 16 + kt) * 512 + lane * 8];
        const s8v b1 = *(const s8v*)&ldsw[(size_t)((2 + u) * 16 + kt) * 512 + lane * 8];
        const s8v b2 = *(const s8v*)&ldsw[(size_t)((4 + u) * 16 + kt) * 512 + lane * 8];
        acc0  = MFMA16(a1[kt], b0, acc0, 0, 0, 0);
        acc1  = MFMA16(a1[kt], b1, acc1, 0, 0, 0);
        acc2x = MFMA16(a1[kt], b2, acc2x, 0, 0, 0);
      }
      asm volatile("s_waitcnt vmcnt(0)" ::: "memory");
      __builtin_amdgcn_sched_barrier(0);   // rule #18: pin hh MFMAs below
#pragma unroll
      for (int kt = 0; kt < 16; ++kt) {
        const s8v av = __builtin_bit_cast(s8v, a2[kt]);
        acc0 = MFMA16(av, bh[0][kt], acc0, 0, 0, 0);
        acc1 = MFMA16(av, bh[1][kt], acc1, 0, 0, 0);
        acc2 = MFMA16(av, bh[2][kt], acc2, 0, 0, 0);
      }

      unsigned hv[4];
#pragma unroll
      for (int r = 0; r < 4; ++r) {
        float rr = fsig(acc0[r] + br);
        float zz = fsig(acc1[r] + bz);
        float nn = ftanh(acc2x[r] + bni + rr * (acc2[r] + bnh));
        float hn = (1.f - zz) * nn + zz * hp[r];
        hp[r] = hn;
        hv[r] = f2bf(hn);
      }

      u16* pb = hbuf + (size_t)(2 + ((t + 1) & 1)) * kPlane + prod_off;
      store_h_l1(pb + (size_t)(mrow + 0) * 8, pb + (size_t)(mrow + 1) * 8,
                 pb + (size_t)(mrow + 2) * 8, pb + (size_t)(mrow + 3) * 8,
                 hv[0], hv[1], hv[2], hv[3]);
      __syncthreads();
      if (tid == 0)
        __hip_atomic_fetch_add(mybar, 1u, __ATOMIC_RELAXED,
                               __HIP_MEMORY_SCOPE_AGENT);
      if (t + 1 < TC) {   // h1 frags for t+1 fly during next wait phase
        const u16* hb = h1base + (size_t)(t + 1) * kPlane;
#pragma unroll
        for (int kt = 0; kt < 16; ++kt)
          a1[kt] = *(const s8v*)(hb + (size_t)kt * 512);
      }
    }
#pragma unroll
    for (int r = 0; r < 4; ++r)
      mycarry[(size_t)(bbase + r) * 512 + jg] = hp[r];
  }
}

// ---------------------------------------------------------------------------
__global__ __launch_bounds__(128)
void fc_kernel(const float* __restrict__ h, const float* __restrict__ wfc,
               const float* __restrict__ bfc, float* __restrict__ out) {
  const int b = blockIdx.x;
  const int n = threadIdx.x;
  const float* hrow = h + (size_t)b * kH;
  const float* wrow = wfc + (size_t)n * kH;
  float acc = 0.f;
#pragma unroll 4
  for (int k = 0; k < kH; k += 4) {
    const float4 hv = *(const float4*)&hrow[k];
    const float4 wv = *(const float4*)&wrow[k];
    acc = fmaf(hv.x, wv.x, acc); acc = fmaf(hv.y, wv.y, acc);
    acc = fmaf(hv.z, wv.z, acc); acc = fmaf(hv.w, wv.w, acc);
  }
  out[(size_t)b * kNOUT + n] = acc + bfc[n];
}

// ---------------------------------------------------------------------------
extern "C" void kernel_launch(void* const* d_in, const int* in_sizes, int n_in,
                              void* d_out, int out_size, void* d_ws, size_t ws_size,
                              hipStream_t stream) {
  const float* x     = (const float*)d_in[0];
  const float* w_ih0 = (const float*)d_in[1];
  const float* w_hh0 = (const float*)d_in[2];
  const float* b_ih0 = (const float*)d_in[3];
  const float* b_hh0 = (const float*)d_in[4];
  const float* w_ih1 = (const float*)d_in[5];
  const float* w_hh1 = (const float*)d_in[6];
  const float* b_ih1 = (const float*)d_in[7];
  const float* b_hh1 = (const float*)d_in[8];
  const float* w_fc  = (const float*)d_in[9];
  const float* b_fc  = (const float*)d_in[10];
  float* out = (float*)d_out;

  // workspace: slabs 4.7 MB + xpl 16.8 MB + h1pl 2*TC*256KB + hbuf 1 MB +
  // carry 1 MB + bar.  TC=64 -> ~57 MB total.
  auto need = [](int tc) -> size_t {
    size_t s = 0;
    s += 3 * (size_t)kG3 * kH * 2;        // slab0hh, slab1hh, slab1ih
    s += (size_t)kG3 * kDIN * 2;          // slab0ih
    s += (size_t)kT * kXStep * 2;         // xpl
    s += 2 * (size_t)tc * kPlane * 2;     // h1pl (chunk-parity dbuf)
    s += 4 * (size_t)kPlane * 2;          // hbuf
    s += 2 * (size_t)kB * kH * 4;         // carry
    s += 65536;
    return s;
  };
  int TC = 64;
  while (TC > 2 && need(TC) > ws_size) TC >>= 1;
  const int nc = kT / TC;

  char* p = (char*)d_ws;
  auto carve = [&](size_t bytes) {
    char* r = p; p += (bytes + 255) & ~(size_t)255; return r;
  };
  u16* slab0hh = (u16*)carve((size_t)kG3 * kH * 2);
  u16* slab1hh = (u16*)carve((size_t)kG3 * kH * 2);
  u16* slab1ih = (u16*)carve((size_t)kG3 * kH * 2);
  u16* slab0ih = (u16*)carve((size_t)kG3 * kDIN * 2);
  u16* xpl     = (u16*)carve((size_t)kT * kXStep * 2);
  u16* h1pl    = (u16*)carve(2 * (size_t)TC * kPlane * 2);
  u16* hbuf    = (u16*)carve(4 * (size_t)kPlane * 2);
  float* carry = (float*)carve(2 * (size_t)kB * kH * 4);
  unsigned* bar = (unsigned*)carve(32 * 64 * sizeof(unsigned));

  // prologue: swizzles + zero h planes/carries + barrier counters
  build_wslab<<<384, 256, 0, stream>>>(w_hh0, slab0hh);
  build_wslab<<<384, 256, 0, stream>>>(w_hh1, slab1hh);
  build_wslab<<<384, 256, 0, stream>>>(w_ih1, slab1ih);
  build_wslab_ih0<<<48, 256, 0, stream>>>(w_ih0, slab0ih);
  build_xplane<<<4096, 256, 0, stream>>>(x, xpl);
  hipMemsetAsync(hbuf, 0, 4 * (size_t)kPlane * 2 + 2 * (size_t)kB * kH * 4, stream);
  hipMemsetAsync(bar, 0, 32 * 64 * sizeof(unsigned), stream);

  // pipeline: dispatch c runs rec0(c) + rec1(c-1); no serial GEMMs.
  for (int c = 0; c <= nc; ++c) {
    unsigned base16 = (unsigned)c * 16u * (unsigned)TC;
    rec_fused<<<dim3(256), dim3(256), 0, stream>>>(
        c, TC, nc, base16, bar, xpl,
        slab0hh, slab0ih, slab1hh, slab1ih,
        b_ih0, b_hh0, b_ih1, b_hh1,
        h1pl, hbuf, carry);
  }

  // final FC on layer-1 terminal state
  fc_kernel<<<dim3(kB), dim3(kNOUT), 0, stream>>>(
      carry + (size_t)kB * kH, w_fc, b_fc, out);
}

// Round 13
// 2216.772 us; speedup vs baseline: 1.1226x; 1.0472x over previous
//
#include <hip/hip_runtime.h>
#include <math.h>

typedef unsigned short u16;
typedef __attribute__((ext_vector_type(8))) short s8v;   // 8 x bf16 (4 VGPRs)
typedef __attribute__((ext_vector_type(4))) float f4v;   // MFMA accumulator
typedef __attribute__((ext_vector_type(4))) int   i4v;   // asm load payload

constexpr int kB    = 256;
constexpr int kT    = 512;
constexpr int kDIN  = 64;
constexpr int kH    = 512;
constexpr int kG3   = 1536;
constexpr int kNOUT = 128;
constexpr int kPlane = 8 * 2 * 16 * 512;   // u16 per h A-frag plane (131072)
constexpr int kXStep = 16 * 2 * 512;       // u16 per x A-frag step (16384)

#define MFMA16 __builtin_amdgcn_mfma_f32_16x16x32_bf16

__device__ __forceinline__ u16 f2bf(float f) {   // round-to-nearest-even
  union { float f; unsigned u; } v; v.f = f;
  unsigned r = (v.u + 0x7FFFu + ((v.u >> 16) & 1u)) >> 16;
  return (u16)r;
}
__device__ __forceinline__ float fsig(float x) {
  x = fminf(fmaxf(x, -30.f), 30.f);
  float e = __expf(-x);
  return __fdividef(1.f, 1.f + e);
}
__device__ __forceinline__ float ftanh(float x) {
  x = fminf(fmaxf(x, -15.f), 15.f);
  float e = __expf(-2.f * x);
  return __fdividef(1.f - e, 1.f + e);
}

// 16 A-fragment loads (16 B/lane, kt stride 1024 B), LLC-coherent bypass,
// NO trailing wait — caller pairs with an explicit vmcnt.
__device__ __forceinline__ void load16_nw(const u16* base, i4v a[16]) {
  asm volatile(
      "global_load_dwordx4 %0, %16, off sc0 sc1\n\t"
      "global_load_dwordx4 %1, %16, off offset:1024 sc0 sc1\n\t"
      "global_load_dwordx4 %2, %16, off offset:2048 sc0 sc1\n\t"
      "global_load_dwordx4 %3, %16, off offset:3072 sc0 sc1\n\t"
      "global_load_dwordx4 %4, %17, off sc0 sc1\n\t"
      "global_load_dwordx4 %5, %17, off offset:1024 sc0 sc1\n\t"
      "global_load_dwordx4 %6, %17, off offset:2048 sc0 sc1\n\t"
      "global_load_dwordx4 %7, %17, off offset:3072 sc0 sc1\n\t"
      "global_load_dwordx4 %8, %18, off sc0 sc1\n\t"
      "global_load_dwordx4 %9, %18, off offset:1024 sc0 sc1\n\t"
      "global_load_dwordx4 %10, %18, off offset:2048 sc0 sc1\n\t"
      "global_load_dwordx4 %11, %18, off offset:3072 sc0 sc1\n\t"
      "global_load_dwordx4 %12, %19, off sc0 sc1\n\t"
      "global_load_dwordx4 %13, %19, off offset:1024 sc0 sc1\n\t"
      "global_load_dwordx4 %14, %19, off offset:2048 sc0 sc1\n\t"
      "global_load_dwordx4 %15, %19, off offset:3072 sc0 sc1"
      : "=&v"(a[0]), "=&v"(a[1]), "=&v"(a[2]), "=&v"(a[3]),
        "=&v"(a[4]), "=&v"(a[5]), "=&v"(a[6]), "=&v"(a[7]),
        "=&v"(a[8]), "=&v"(a[9]), "=&v"(a[10]), "=&v"(a[11]),
        "=&v"(a[12]), "=&v"(a[13]), "=&v"(a[14]), "=&v"(a[15])
      : "v"(base), "v"(base + 4 * 512), "v"(base + 8 * 512), "v"(base + 12 * 512)
      : "memory");
}

// L0 publish: 4 hbuf coherent + 4 h1pl coherent stores, FULL drain — the
// arrive that follows must imply h1pl visibility at the LLC (no kernel
// boundary to flush it anymore).
__device__ __forceinline__ void store8c(
    u16* p0, u16* p1, u16* p2, u16* p3,
    u16* q0, u16* q1, u16* q2, u16* q3,
    unsigned v0, unsigned v1, unsigned v2, unsigned v3) {
  asm volatile(
      "global_store_short %0, %8, off sc0 sc1\n\t"
      "global_store_short %1, %9, off sc0 sc1\n\t"
      "global_store_short %2, %10, off sc0 sc1\n\t"
      "global_store_short %3, %11, off sc0 sc1\n\t"
      "global_store_short %4, %8, off sc0 sc1\n\t"
      "global_store_short %5, %9, off sc0 sc1\n\t"
      "global_store_short %6, %10, off sc0 sc1\n\t"
      "global_store_short %7, %11, off sc0 sc1\n\t"
      "s_waitcnt vmcnt(0)"
      :: "v"(p0), "v"(p1), "v"(p2), "v"(p3),
         "v"(q0), "v"(q1), "v"(q2), "v"(q3),
         "v"(v0), "v"(v1), "v"(v2), "v"(v3)
      : "memory");
}
// Layer-1: 4 coherent stores + full drain. (Verified r0/r5/r12.)
__device__ __forceinline__ void store_h_l1(
    u16* p0, u16* p1, u16* p2, u16* p3,
    unsigned v0, unsigned v1, unsigned v2, unsigned v3) {
  asm volatile(
      "global_store_short %0, %4, off sc0 sc1\n\t"
      "global_store_short %1, %5, off sc0 sc1\n\t"
      "global_store_short %2, %6, off sc0 sc1\n\t"
      "global_store_short %3, %7, off sc0 sc1\n\t"
      "s_waitcnt vmcnt(0)"
      :: "v"(p0), "v"(p1), "v"(p2), "v"(p3),
         "v"(v0), "v"(v1), "v"(v2), "v"(v3)
      : "memory");
}

// ---------------------------------------------------------------------------
// B-frag slab for [1536][512] fp32 weights (w_hh0, w_hh1, w_ih1).
// Layout: [jt 16][f 96][lane 64][8], f = (g*2+u)*16 + kt.  (Verified r0-r12.)
// ---------------------------------------------------------------------------
__global__ void build_wslab(const float* __restrict__ w, u16* __restrict__ d) {
  int idx  = blockIdx.x * 256 + threadIdx.x;   // 0..98303
  int lane = idx & 63, fg = idx >> 6;          // fg = jt*96 + f
  int jt = fg / 96, f = fg % 96;
  int nt = f >> 4, kt = f & 15;
  int g = nt >> 1, u = nt & 1;
  int row = g * 512 + jt * 32 + u * 16 + (lane & 15);
  int k0  = kt * 32 + (lane >> 4) * 8;
  const float* src = w + (size_t)row * 512 + k0;
  u16* dst = d + ((size_t)fg) * 512 + lane * 8;
#pragma unroll
  for (int i = 0; i < 8; i++) dst[i] = f2bf(src[i]);
}

// B-frag slab for w_ih0 [1536][64]: [jt 16][f 12][lane 64][8], f=(g*2+u)*2+kt.
// (Verified r4-r12.)
__global__ void build_wslab_ih0(const float* __restrict__ w, u16* __restrict__ d) {
  int idx  = blockIdx.x * 256 + threadIdx.x;   // 0..12287
  int lane = idx & 63, fg = idx >> 6;          // fg = jt*12 + f
  int jt = fg / 12, f = fg % 12;
  int nt = f >> 1, kt = f & 1;
  int g = nt >> 1, u = nt & 1;
  int row = g * 512 + jt * 32 + u * 16 + (lane & 15);
  int k0  = kt * 32 + (lane >> 4) * 8;
  const float* src = w + (size_t)row * kDIN + k0;
  u16* dst = d + ((size_t)fg) * 512 + lane * 8;
#pragma unroll
  for (int i = 0; i < 8; i++) dst[i] = f2bf(src[i]);
}

// x [256][512][64] fp32 -> per-step A-frag planes (bf16). (Verified r4-r12.)
__global__ void build_xplane(const float* __restrict__ x, u16* __restrict__ d) {
  int idx  = blockIdx.x * 256 + threadIdx.x;   // 0..1048575
  int lane = idx & 63, fg = idx >> 6;          // fg = (T*16+m)*2+kt
  int kt = fg & 1, m = (fg >> 1) & 15, T = fg >> 5;
  int b  = m * 16 + (lane & 15);
  int k0 = kt * 32 + (lane >> 4) * 8;
  const float* src = x + ((size_t)b * kT + T) * kDIN + k0;
  u16* dst = d + ((size_t)fg) * 512 + lane * 8;
#pragma unroll
  for (int i = 0; i < 8; i++) dst[i] = f2bf(src[i]);
}

// ---------------------------------------------------------------------------
// SINGLE persistent dispatch, write-once h1pl (512 unique planes, 128 MB).
// Blocks 0..127: layer0 all 512 steps (fused proj0 via xplane). Blocks
// 128..255: layer1 all 512 steps (fused proj1: h1pl A-frags + LDS w_ih1).
//
// Dependency structure (acyclic, deadlock-free):
//   - L0: own-group barrier only (byte-identical r12 protocol). It NEVER
//     waits on L1 — h1pl is write-once, so no WAR exists.
//   - L1 step s: own-group barrier (r12) + gate barL0 >= 16(s+2), i.e.
//     L0 finished step s+1 — which covers this step's a1 use (plane s,
//     loaded last step) AND the end-of-step prefetch of plane s+1.
//     One-directional, slack-growing (L1's slot >= L0's): after warmup the
//     gate is pre-satisfied and off the chain.
// Visibility without kernel boundaries: L0's h1pl stores are sc0|sc1 and
// FULLY drained before its arrive (store8c); L1 reads h1pl with the
// sc0|sc1 asm loader + the r7-verified vmcnt(16) pairing (a1 issued before
// a2; vmcnt retires oldest-first).
// Single dispatch deletes: 8 launches, 8x weight/LDS/carry reloads, and
// the TC=64-step pipeline lag tail (now ~2 steps).
// ---------------------------------------------------------------------------
__global__ __launch_bounds__(256, 1)
void rec_all(unsigned* bar, const u16* __restrict__ xpl,
             const u16* __restrict__ slab0hh, const u16* __restrict__ slab0ih,
             const u16* __restrict__ slab1hh, const u16* __restrict__ slab1ih,
             const float* __restrict__ bih0, const float* __restrict__ bhh0,
             const float* __restrict__ bih1, const float* __restrict__ bhh1,
             u16* __restrict__ h1pl, u16* __restrict__ hbuf,
             float* __restrict__ carry) {
  __shared__ u16 ldsw[96 * 512];   // layer1: w_ih1 jt-slice (96 KB)

  const int bid   = blockIdx.x;
  const int layer = bid >> 7;
  const int lb    = bid & 127;
  const int jt    = lb & 15, bt = lb >> 4;

  unsigned* barL0 = bar + (size_t)bt * 64;          // own cacheline per group
  unsigned* barL1 = bar + (size_t)(8 + bt) * 64;
  unsigned* mybar = layer ? barL1 : barL0;

  const int tid   = threadIdx.x;
  const int wv    = tid >> 6, lane = tid & 63;
  const int mt    = wv >> 1, u = wv & 1;
  const int jl    = lane & 15;
  const int jg    = jt * 32 + u * 16 + jl;
  const int mrow  = (lane >> 4) * 4;
  const int bbase = bt * 32 + mt * 16 + mrow;

  const size_t cons_off = ((size_t)((bt * 2 + mt) * 16)) * 512 + lane * 8;
  const size_t prod_off = ((size_t)((bt * 2 + mt) * 16 + jt)) * 512 +
                          (size_t)(16 * (u * 2 + (jl >> 3))) * 8 + (jl & 7);

  if (layer == 0) {
    // ---- resident: w_hh0 (48 frags) + w_ih0 (6 frags) ----
    s8v bh[3][16];
    {
      const u16* base = slab0hh + (size_t)jt * 96 * 512 + (size_t)lane * 8;
#pragma unroll
      for (int g = 0; g < 3; ++g)
#pragma unroll
        for (int kt = 0; kt < 16; ++kt)
          bh[g][kt] = *(const s8v*)(base + (size_t)((g * 2 + u) * 16 + kt) * 512);
    }
    s8v bx[3][2];
    {
      const u16* base = slab0ih + (size_t)jt * 12 * 512 + (size_t)lane * 8;
#pragma unroll
      for (int g = 0; g < 3; ++g)
#pragma unroll
        for (int kt = 0; kt < 2; ++kt)
          bx[g][kt] = *(const s8v*)(base + (size_t)((g * 2 + u) * 2 + kt) * 512);
    }
    const float br  = bih0[jg] + bhh0[jg];
    const float bz  = bih0[512 + jg] + bhh0[512 + jg];
    const float bni = bih0[1024 + jg], bnh = bhh0[1024 + jg];
    float hp[4] = {0.f, 0.f, 0.f, 0.f};

    const size_t xoff = (size_t)((bt * 2 + mt) * 2) * 512 + (size_t)lane * 8;
    s8v ax0 = *(const s8v*)(xpl + xoff);
    s8v ax1 = *(const s8v*)(xpl + xoff + 512);

    for (int t = 0; t < kT; ++t) {
      if (tid == 0 && t) {
        unsigned tgt = 16u * (unsigned)t;
        int guard = 0;
        while (__hip_atomic_load(barL0, __ATOMIC_RELAXED,
                                 __HIP_MEMORY_SCOPE_AGENT) < tgt
               && ++guard < (1 << 21))
          __builtin_amdgcn_s_sleep(1);
      }
      __syncthreads();

      // issue h1_{t-1} loads; x MFMAs run under the LLC latency
      i4v a[16];
      load16_nw(hbuf + (size_t)(t & 1) * kPlane + cons_off, a);

      const f4v z4 = {0.f, 0.f, 0.f, 0.f};
      f4v acc0, acc1, acc2, acc2x;
      acc0  = MFMA16(ax0, bx[0][0], z4, 0, 0, 0);
      acc0  = MFMA16(ax1, bx[0][1], acc0, 0, 0, 0);
      acc1  = MFMA16(ax0, bx[1][0], z4, 0, 0, 0);
      acc1  = MFMA16(ax1, bx[1][1], acc1, 0, 0, 0);
      acc2x = MFMA16(ax0, bx[2][0], z4, 0, 0, 0);
      acc2x = MFMA16(ax1, bx[2][1], acc2x, 0, 0, 0);
      acc2  = z4;
      asm volatile("s_waitcnt vmcnt(0)" ::: "memory");
      __builtin_amdgcn_sched_barrier(0);   // rule #18: pin hh MFMAs below
#pragma unroll
      for (int kt = 0; kt < 16; ++kt) {
        const s8v av = __builtin_bit_cast(s8v, a[kt]);
        acc0 = MFMA16(av, bh[0][kt], acc0, 0, 0, 0);
        acc1 = MFMA16(av, bh[1][kt], acc1, 0, 0, 0);
        acc2 = MFMA16(av, bh[2][kt], acc2, 0, 0, 0);
      }

      unsigned hv[4];
#pragma unroll
      for (int r = 0; r < 4; ++r) {
        float rr = fsig(acc0[r] + br);
        float zz = fsig(acc1[r] + bz);
        float nn = ftanh(acc2x[r] + bni + rr * (acc2[r] + bnh));
        float hn = (1.f - zz) * nn + zz * hp[r];
        hp[r] = hn;
        hv[r] = f2bf(hn);
      }

      // publish h1_t: hbuf (group exchange) + h1pl plane t (write-once);
      // full drain so the arrive implies LLC visibility of both.
      u16* pb = hbuf + (size_t)((t + 1) & 1) * kPlane + prod_off;
      u16* qb = h1pl + (size_t)t * kPlane + prod_off;
      store8c(pb + (size_t)(mrow + 0) * 8, pb + (size_t)(mrow + 1) * 8,
              pb + (size_t)(mrow + 2) * 8, pb + (size_t)(mrow + 3) * 8,
              qb + (size_t)(mrow + 0) * 8, qb + (size_t)(mrow + 1) * 8,
              qb + (size_t)(mrow + 2) * 8, qb + (size_t)(mrow + 3) * 8,
              hv[0], hv[1], hv[2], hv[3]);
      __syncthreads();
      if (tid == 0)
        __hip_atomic_fetch_add(barL0, 1u, __ATOMIC_RELAXED,
                               __HIP_MEMORY_SCOPE_AGENT);
      if (t + 1 < kT) {   // x frags for t+1 fly during next wait phase
        const u16* xb = xpl + (size_t)(t + 1) * kXStep + xoff;
        ax0 = *(const s8v*)xb;
        ax1 = *(const s8v*)(xb + 512);
      }
    }
  } else {
    // ---- w_ih1 jt-slice -> LDS (once); w_hh1 resident in VGPRs ----
    {
      const u16* src = slab1ih + (size_t)jt * 96 * 512;
      for (int i = tid; i < 96 * 512 / 8; i += 256)
        *(s8v*)&ldsw[i * 8] = *(const s8v*)&src[i * 8];
    }
    s8v bh[3][16];
    {
      const u16* base = slab1hh + (size_t)jt * 96 * 512 + (size_t)lane * 8;
#pragma unroll
      for (int g = 0; g < 3; ++g)
#pragma unroll
        for (int kt = 0; kt < 16; ++kt)
          bh[g][kt] = *(const s8v*)(base + (size_t)((g * 2 + u) * 16 + kt) * 512);
    }
    const float br  = bih1[jg] + bhh1[jg];
    const float bz  = bih1[512 + jg] + bhh1[512 + jg];
    const float bni = bih1[1024 + jg], bnh = bhh1[1024 + jg];
    float hp[4] = {0.f, 0.f, 0.f, 0.f};

    const u16* h1base = h1pl + cons_off;   // plane s at + s*kPlane
    i4v a1[16];                            // persistent across steps

    for (int s = 0; s < kT; ++s) {
      if (tid == 0 && s) {
        unsigned tgt = 16u * (unsigned)s;
        int guard = 0;
        while (__hip_atomic_load(barL1, __ATOMIC_RELAXED,
                                 __HIP_MEMORY_SCOPE_AGENT) < tgt
               && ++guard < (1 << 21))
          __builtin_amdgcn_s_sleep(1);
      } else if (tid == 64) {
        unsigned tgt = 16u * (unsigned)((s + 2 <= kT) ? (s + 2) : kT);
        int guard = 0;
        while (__hip_atomic_load(barL0, __ATOMIC_RELAXED,
                                 __HIP_MEMORY_SCOPE_AGENT) < tgt
               && ++guard < (1 << 21))
          __builtin_amdgcn_s_sleep(1);
      }
      __syncthreads();   // also orders the LDS fill before first ds_read

      // step 0: a1 (plane 0) has no prior prefetch — issue it FIRST so the
      // vmcnt(16) pairing below completes it while a2 stays in flight.
      if (s == 0) load16_nw(h1base, a1);

      // issue h2_{s-1} loads; vmcnt(16) completes ONLY the older a1 set;
      // ih MFMAs then run under a2's LLC latency (r7-verified pairing).
      i4v a2[16];
      load16_nw(hbuf + (size_t)(2 + (s & 1)) * kPlane + cons_off, a2);
      asm volatile("s_waitcnt vmcnt(16)" ::: "memory");
      __builtin_amdgcn_sched_barrier(0);   // rule #18: pin ih MFMAs below

      const f4v z4 = {0.f, 0.f, 0.f, 0.f};
      f4v acc0 = z4, acc1 = z4, acc2 = z4, acc2x = z4;
#pragma unroll
      for (int kt = 0; kt < 16; ++kt) {
        const s8v b0 = *(const s8v*)&ldsw[(size_t)((0 + u) * 16 + kt) * 512 + lane * 8];
        const s8v b1 = *(const s8v*)&ldsw[(size_t)((2 + u) * 16 + kt) * 512 + lane * 8];
        const s8v b2 = *(const s8v*)&ldsw[(size_t)((4 + u) * 16 + kt) * 512 + lane * 8];
        const s8v av = __builtin_bit_cast(s8v, a1[kt]);
        acc0  = MFMA16(av, b0, acc0, 0, 0, 0);
        acc1  = MFMA16(av, b1, acc1, 0, 0, 0);
        acc2x = MFMA16(av, b2, acc2x, 0, 0, 0);
      }
      asm volatile("s_waitcnt vmcnt(0)" ::: "memory");
      __builtin_amdgcn_sched_barrier(0);   // rule #18: pin hh MFMAs below
#pragma unroll
      for (int kt = 0; kt < 16; ++kt) {
        const s8v av = __builtin_bit_cast(s8v, a2[kt]);
        acc0 = MFMA16(av, bh[0][kt], acc0, 0, 0, 0);
        acc1 = MFMA16(av, bh[1][kt], acc1, 0, 0, 0);
        acc2 = MFMA16(av, bh[2][kt], acc2, 0, 0, 0);
      }

      unsigned hv[4];
#pragma unroll
      for (int r = 0; r < 4; ++r) {
        float rr = fsig(acc0[r] + br);
        float zz = fsig(acc1[r] + bz);
        float nn = ftanh(acc2x[r] + bni + rr * (acc2[r] + bnh));
        float hn = (1.f - zz) * nn + zz * hp[r];
        hp[r] = hn;
        hv[r] = f2bf(hn);
      }

      u16* pb = hbuf + (size_t)(2 + ((s + 1) & 1)) * kPlane + prod_off;
      store_h_l1(pb + (size_t)(mrow + 0) * 8, pb + (size_t)(mrow + 1) * 8,
                 pb + (size_t)(mrow + 2) * 8, pb + (size_t)(mrow + 3) * 8,
                 hv[0], hv[1], hv[2], hv[3]);
      __syncthreads();
      if (tid == 0)
        __hip_atomic_fetch_add(barL1, 1u, __ATOMIC_RELAXED,
                               __HIP_MEMORY_SCOPE_AGENT);
      // prefetch a1 for s+1 (plane s+1, written by L0 step s+1 — covered by
      // THIS step's gate barL0 >= 16(s+2)); flies across next wait phase.
      if (s + 1 < kT)
        load16_nw(h1base + (size_t)(s + 1) * kPlane, a1);
    }

    // final h2 -> carry (fp32) for the FC
#pragma unroll
    for (int r = 0; r < 4; ++r)
      carry[(size_t)(bbase + r) * 512 + jg] = hp[r];
  }
}

// ---------------------------------------------------------------------------
__global__ __launch_bounds__(128)
void fc_kernel(const float* __restrict__ h, const float* __restrict__ wfc,
               const float* __restrict__ bfc, float* __restrict__ out) {
  const int b = blockIdx.x;
  const int n = threadIdx.x;
  const float* hrow = h + (size_t)b * kH;
  const float* wrow = wfc + (size_t)n * kH;
  float acc = 0.f;
#pragma unroll 4
  for (int k = 0; k < kH; k += 4) {
    const float4 hv = *(const float4*)&hrow[k];
    const float4 wv = *(const float4*)&wrow[k];
    acc = fmaf(hv.x, wv.x, acc); acc = fmaf(hv.y, wv.y, acc);
    acc = fmaf(hv.z, wv.z, acc); acc = fmaf(hv.w, wv.w, acc);
  }
  out[(size_t)b * kNOUT + n] = acc + bfc[n];
}

// ---------------------------------------------------------------------------
extern "C" void kernel_launch(void* const* d_in, const int* in_sizes, int n_in,
                              void* d_out, int out_size, void* d_ws, size_t ws_size,
                              hipStream_t stream) {
  const float* x     = (const float*)d_in[0];
  const float* w_ih0 = (const float*)d_in[1];
  const float* w_hh0 = (const float*)d_in[2];
  const float* b_ih0 = (const float*)d_in[3];
  const float* b_hh0 = (const float*)d_in[4];
  const float* w_ih1 = (const float*)d_in[5];
  const float* w_hh1 = (const float*)d_in[6];
  const float* b_ih1 = (const float*)d_in[7];
  const float* b_hh1 = (const float*)d_in[8];
  const float* w_fc  = (const float*)d_in[9];
  const float* b_fc  = (const float*)d_in[10];
  float* out = (float*)d_out;

  // workspace: slabs 4.7 MB + xpl 16.8 MB + h1pl 128 MB (512 write-once
  // planes) + hbuf 1 MB + carry 0.5 MB + bar ~= 151 MB total.
  // (ws >= ~240 MB proven by the round-0 kernel's TC=64 allocation.)
  char* p = (char*)d_ws;
  auto carve = [&](size_t bytes) {
    char* r = p; p += (bytes + 255) & ~(size_t)255; return r;
  };
  u16* slab0hh = (u16*)carve((size_t)kG3 * kH * 2);
  u16* slab1hh = (u16*)carve((size_t)kG3 * kH * 2);
  u16* slab1ih = (u16*)carve((size_t)kG3 * kH * 2);
  u16* slab0ih = (u16*)carve((size_t)kG3 * kDIN * 2);
  u16* xpl     = (u16*)carve((size_t)kT * kXStep * 2);
  u16* h1pl    = (u16*)carve((size_t)kT * kPlane * 2);   // 128 MB, write-once
  u16* hbuf    = (u16*)carve(4 * (size_t)kPlane * 2);
  float* carry = (float*)carve((size_t)kB * kH * 4);
  unsigned* bar = (unsigned*)carve(16 * 64 * sizeof(unsigned));

  // prologue: swizzles + zero h planes + barrier counters
  build_wslab<<<384, 256, 0, stream>>>(w_hh0, slab0hh);
  build_wslab<<<384, 256, 0, stream>>>(w_hh1, slab1hh);
  build_wslab<<<384, 256, 0, stream>>>(w_ih1, slab1ih);
  build_wslab_ih0<<<48, 256, 0, stream>>>(w_ih0, slab0ih);
  build_xplane<<<4096, 256, 0, stream>>>(x, xpl);
  hipMemsetAsync(hbuf, 0, 4 * (size_t)kPlane * 2, stream);
  hipMemsetAsync(bar, 0, 16 * 64 * sizeof(unsigned), stream);

  // the whole 2-layer recurrence in ONE persistent dispatch
  rec_all<<<dim3(256), dim3(256), 0, stream>>>(
      bar, xpl, slab0hh, slab0ih, slab1hh, slab1ih,
      b_ih0, b_hh0, b_ih1, b_hh1, h1pl, hbuf, carry);

  // final FC on layer-1 terminal state
  fc_kernel<<<dim3(kB), dim3(kNOUT), 0, stream>>>(carry, w_fc, b_fc, out);
}

// Round 14
// 2191.717 us; speedup vs baseline: 1.1354x; 1.0114x over previous
//
#include <hip/hip_runtime.h>
#include <math.h>

typedef unsigned short u16;
typedef __attribute__((ext_vector_type(8))) short s8v;   // 8 x bf16 (4 VGPRs)
typedef __attribute__((ext_vector_type(4))) float f4v;   // MFMA accumulator
typedef __attribute__((ext_vector_type(4))) int   i4v;   // asm load payload

constexpr int kB    = 256;
constexpr int kT    = 512;
constexpr int kDIN  = 64;
constexpr int kH    = 512;
constexpr int kG3   = 1536;
constexpr int kNOUT = 128;
constexpr int kPlane = 8 * 2 * 16 * 512;   // u16 per h A-frag plane (131072)
constexpr int kXStep = 16 * 2 * 512;       // u16 per x A-frag step (16384)

#define MFMA16 __builtin_amdgcn_mfma_f32_16x16x32_bf16

__device__ __forceinline__ u16 f2bf(float f) {   // round-to-nearest-even
  union { float f; unsigned u; } v; v.f = f;
  unsigned r = (v.u + 0x7FFFu + ((v.u >> 16) & 1u)) >> 16;
  return (u16)r;
}
__device__ __forceinline__ float fsig(float x) {
  x = fminf(fmaxf(x, -30.f), 30.f);
  float e = __expf(-x);
  return __fdividef(1.f, 1.f + e);
}
__device__ __forceinline__ float ftanh(float x) {
  x = fminf(fmaxf(x, -15.f), 15.f);
  float e = __expf(-2.f * x);
  return __fdividef(1.f - e, 1.f + e);
}

// 16 A-fragment loads (16 B/lane, kt stride 1024 B), LLC-coherent bypass,
// NO trailing wait — caller pairs with an explicit vmcnt.
__device__ __forceinline__ void load16_nw(const u16* base, i4v a[16]) {
  asm volatile(
      "global_load_dwordx4 %0, %16, off sc0 sc1\n\t"
      "global_load_dwordx4 %1, %16, off offset:1024 sc0 sc1\n\t"
      "global_load_dwordx4 %2, %16, off offset:2048 sc0 sc1\n\t"
      "global_load_dwordx4 %3, %16, off offset:3072 sc0 sc1\n\t"
      "global_load_dwordx4 %4, %17, off sc0 sc1\n\t"
      "global_load_dwordx4 %5, %17, off offset:1024 sc0 sc1\n\t"
      "global_load_dwordx4 %6, %17, off offset:2048 sc0 sc1\n\t"
      "global_load_dwordx4 %7, %17, off offset:3072 sc0 sc1\n\t"
      "global_load_dwordx4 %8, %18, off sc0 sc1\n\t"
      "global_load_dwordx4 %9, %18, off offset:1024 sc0 sc1\n\t"
      "global_load_dwordx4 %10, %18, off offset:2048 sc0 sc1\n\t"
      "global_load_dwordx4 %11, %18, off offset:3072 sc0 sc1\n\t"
      "global_load_dwordx4 %12, %19, off sc0 sc1\n\t"
      "global_load_dwordx4 %13, %19, off offset:1024 sc0 sc1\n\t"
      "global_load_dwordx4 %14, %19, off offset:2048 sc0 sc1\n\t"
      "global_load_dwordx4 %15, %19, off offset:3072 sc0 sc1"
      : "=&v"(a[0]), "=&v"(a[1]), "=&v"(a[2]), "=&v"(a[3]),
        "=&v"(a[4]), "=&v"(a[5]), "=&v"(a[6]), "=&v"(a[7]),
        "=&v"(a[8]), "=&v"(a[9]), "=&v"(a[10]), "=&v"(a[11]),
        "=&v"(a[12]), "=&v"(a[13]), "=&v"(a[14]), "=&v"(a[15])
      : "v"(base), "v"(base + 4 * 512), "v"(base + 8 * 512), "v"(base + 12 * 512)
      : "memory");
}

// L0 publish, LAZY h1pl drain (r12-verified chain cost): 4 hbuf coherent
// stores FIRST, then 4 h1pl coherent stores, then vmcnt(4) — waits only the
// hbuf 4 (in-order retirement); h1pl drains during the barrier round. The
// consumer compensates with a gate of s+3 (see rec_all header).
__device__ __forceinline__ void store_h_l0(
    u16* p0, u16* p1, u16* p2, u16* p3,
    u16* q0, u16* q1, u16* q2, u16* q3,
    unsigned v0, unsigned v1, unsigned v2, unsigned v3) {
  asm volatile(
      "global_store_short %0, %8, off sc0 sc1\n\t"
      "global_store_short %1, %9, off sc0 sc1\n\t"
      "global_store_short %2, %10, off sc0 sc1\n\t"
      "global_store_short %3, %11, off sc0 sc1\n\t"
      "global_store_short %4, %8, off sc0 sc1\n\t"
      "global_store_short %5, %9, off sc0 sc1\n\t"
      "global_store_short %6, %10, off sc0 sc1\n\t"
      "global_store_short %7, %11, off sc0 sc1\n\t"
      "s_waitcnt vmcnt(4)"
      :: "v"(p0), "v"(p1), "v"(p2), "v"(p3),
         "v"(q0), "v"(q1), "v"(q2), "v"(q3),
         "v"(v0), "v"(v1), "v"(v2), "v"(v3)
      : "memory");
}
// Layer-1: 4 coherent stores + full drain. (Verified r0/r5/r12/r13.)
__device__ __forceinline__ void store_h_l1(
    u16* p0, u16* p1, u16* p2, u16* p3,
    unsigned v0, unsigned v1, unsigned v2, unsigned v3) {
  asm volatile(
      "global_store_short %0, %4, off sc0 sc1\n\t"
      "global_store_short %1, %5, off sc0 sc1\n\t"
      "global_store_short %2, %6, off sc0 sc1\n\t"
      "global_store_short %3, %7, off sc0 sc1\n\t"
      "s_waitcnt vmcnt(0)"
      :: "v"(p0), "v"(p1), "v"(p2), "v"(p3),
         "v"(v0), "v"(v1), "v"(v2), "v"(v3)
      : "memory");
}

// ---------------------------------------------------------------------------
// B-frag slab for [1536][512] fp32 weights (w_hh0, w_hh1, w_ih1).
// Layout: [jt 16][f 96][lane 64][8], f = (g*2+u)*16 + kt.  (Verified r0-r13.)
// ---------------------------------------------------------------------------
__global__ void build_wslab(const float* __restrict__ w, u16* __restrict__ d) {
  int idx  = blockIdx.x * 256 + threadIdx.x;   // 0..98303
  int lane = idx & 63, fg = idx >> 6;          // fg = jt*96 + f
  int jt = fg / 96, f = fg % 96;
  int nt = f >> 4, kt = f & 15;
  int g = nt >> 1, u = nt & 1;
  int row = g * 512 + jt * 32 + u * 16 + (lane & 15);
  int k0  = kt * 32 + (lane >> 4) * 8;
  const float* src = w + (size_t)row * 512 + k0;
  u16* dst = d + ((size_t)fg) * 512 + lane * 8;
#pragma unroll
  for (int i = 0; i < 8; i++) dst[i] = f2bf(src[i]);
}

// B-frag slab for w_ih0 [1536][64]: [jt 16][f 12][lane 64][8], f=(g*2+u)*2+kt.
// (Verified r4-r13.)
__global__ void build_wslab_ih0(const float* __restrict__ w, u16* __restrict__ d) {
  int idx  = blockIdx.x * 256 + threadIdx.x;   // 0..12287
  int lane = idx & 63, fg = idx >> 6;          // fg = jt*12 + f
  int jt = fg / 12, f = fg % 12;
  int nt = f >> 1, kt = f & 1;
  int g = nt >> 1, u = nt & 1;
  int row = g * 512 + jt * 32 + u * 16 + (lane & 15);
  int k0  = kt * 32 + (lane >> 4) * 8;
  const float* src = w + (size_t)row * kDIN + k0;
  u16* dst = d + ((size_t)fg) * 512 + lane * 8;
#pragma unroll
  for (int i = 0; i < 8; i++) dst[i] = f2bf(src[i]);
}

// x [256][512][64] fp32 -> per-step A-frag planes (bf16). (Verified r4-r13.)
__global__ void build_xplane(const float* __restrict__ x, u16* __restrict__ d) {
  int idx  = blockIdx.x * 256 + threadIdx.x;   // 0..1048575
  int lane = idx & 63, fg = idx >> 6;          // fg = (T*16+m)*2+kt
  int kt = fg & 1, m = (fg >> 1) & 15, T = fg >> 5;
  int b  = m * 16 + (lane & 15);
  int k0 = kt * 32 + (lane >> 4) * 8;
  const float* src = x + ((size_t)b * kT + T) * kDIN + k0;
  u16* dst = d + ((size_t)fg) * 512 + lane * 8;
#pragma unroll
  for (int i = 0; i < 8; i++) dst[i] = f2bf(src[i]);
}

// ---------------------------------------------------------------------------
// SINGLE persistent dispatch, write-once h1pl (512 unique planes, 128 MB).
// Blocks 0..127: layer0 all 512 steps (fused proj0 via xplane). Blocks
// 128..255: layer1 all 512 steps (fused proj1: h1pl A-frags + LDS w_ih1).
//
// ROUND-14 delta vs the PASSING r13 (one mechanism, L0-chain cost):
// L0's publish uses the r12-verified LAZY h1pl drain (vmcnt(4)) instead of
// r13's full drain — removes one store-ack round from L0's chain (the
// dispatch pacer; r12 slot 4.13 vs r13 4.28 us). Consumer compensation:
//   - L1 gate: barL0 >= 16*min(s+3, kT+1). L0's arrive(s+2) follows
//     publish(s+2)'s vmcnt(4), which (in-order retirement) guarantees
//     publish(s+1)'s h1pl stores — plane s+1, exactly what the prefetch
//     issued at the end of L1 step s reads. Step-0 gate (=48) covers
//     planes 0-1 for the initial a1 load + first prefetch.
//   - Tail: after its loop, L0 drains everything (per-wave vmcnt(0) +
//     __syncthreads) and arrives ONCE more (barL0 -> 16*(kT+1)), so the
//     s=kT-2 gate covers plane kT-1's lazy stores.
// All other protocol, loads, stores: byte-identical to r13 (passed).
// ---------------------------------------------------------------------------
__global__ __launch_bounds__(256, 1)
void rec_all(unsigned* bar, const u16* __restrict__ xpl,
             const u16* __restrict__ slab0hh, const u16* __restrict__ slab0ih,
             const u16* __restrict__ slab1hh, const u16* __restrict__ slab1ih,
             const float* __restrict__ bih0, const float* __restrict__ bhh0,
             const float* __restrict__ bih1, const float* __restrict__ bhh1,
             u16* __restrict__ h1pl, u16* __restrict__ hbuf,
             float* __restrict__ carry) {
  __shared__ u16 ldsw[96 * 512];   // layer1: w_ih1 jt-slice (96 KB)

  const int bid   = blockIdx.x;
  const int layer = bid >> 7;
  const int lb    = bid & 127;
  const int jt    = lb & 15, bt = lb >> 4;

  unsigned* barL0 = bar + (size_t)bt * 64;          // own cacheline per group
  unsigned* barL1 = bar + (size_t)(8 + bt) * 64;

  const int tid   = threadIdx.x;
  const int wv    = tid >> 6, lane = tid & 63;
  const int mt    = wv >> 1, u = wv & 1;
  const int jl    = lane & 15;
  const int jg    = jt * 32 + u * 16 + jl;
  const int mrow  = (lane >> 4) * 4;
  const int bbase = bt * 32 + mt * 16 + mrow;

  const size_t cons_off = ((size_t)((bt * 2 + mt) * 16)) * 512 + lane * 8;
  const size_t prod_off = ((size_t)((bt * 2 + mt) * 16 + jt)) * 512 +
                          (size_t)(16 * (u * 2 + (jl >> 3))) * 8 + (jl & 7);

  if (layer == 0) {
    // ---- resident: w_hh0 (48 frags) + w_ih0 (6 frags) ----
    s8v bh[3][16];
    {
      const u16* base = slab0hh + (size_t)jt * 96 * 512 + (size_t)lane * 8;
#pragma unroll
      for (int g = 0; g < 3; ++g)
#pragma unroll
        for (int kt = 0; kt < 16; ++kt)
          bh[g][kt] = *(const s8v*)(base + (size_t)((g * 2 + u) * 16 + kt) * 512);
    }
    s8v bx[3][2];
    {
      const u16* base = slab0ih + (size_t)jt * 12 * 512 + (size_t)lane * 8;
#pragma unroll
      for (int g = 0; g < 3; ++g)
#pragma unroll
        for (int kt = 0; kt < 2; ++kt)
          bx[g][kt] = *(const s8v*)(base + (size_t)((g * 2 + u) * 2 + kt) * 512);
    }
    const float br  = bih0[jg] + bhh0[jg];
    const float bz  = bih0[512 + jg] + bhh0[512 + jg];
    const float bni = bih0[1024 + jg], bnh = bhh0[1024 + jg];
    float hp[4] = {0.f, 0.f, 0.f, 0.f};

    const size_t xoff = (size_t)((bt * 2 + mt) * 2) * 512 + (size_t)lane * 8;
    s8v ax0 = *(const s8v*)(xpl + xoff);
    s8v ax1 = *(const s8v*)(xpl + xoff + 512);

    for (int t = 0; t < kT; ++t) {
      if (tid == 0 && t) {
        unsigned tgt = 16u * (unsigned)t;
        int guard = 0;
        while (__hip_atomic_load(barL0, __ATOMIC_RELAXED,
                                 __HIP_MEMORY_SCOPE_AGENT) < tgt
               && ++guard < (1 << 21))
          __builtin_amdgcn_s_sleep(1);
      }
      __syncthreads();

      // issue h1_{t-1} loads; x MFMAs run under the LLC latency
      i4v a[16];
      load16_nw(hbuf + (size_t)(t & 1) * kPlane + cons_off, a);

      const f4v z4 = {0.f, 0.f, 0.f, 0.f};
      f4v acc0, acc1, acc2, acc2x;
      acc0  = MFMA16(ax0, bx[0][0], z4, 0, 0, 0);
      acc0  = MFMA16(ax1, bx[0][1], acc0, 0, 0, 0);
      acc1  = MFMA16(ax0, bx[1][0], z4, 0, 0, 0);
      acc1  = MFMA16(ax1, bx[1][1], acc1, 0, 0, 0);
      acc2x = MFMA16(ax0, bx[2][0], z4, 0, 0, 0);
      acc2x = MFMA16(ax1, bx[2][1], acc2x, 0, 0, 0);
      acc2  = z4;
      asm volatile("s_waitcnt vmcnt(0)" ::: "memory");
      __builtin_amdgcn_sched_barrier(0);   // rule #18: pin hh MFMAs below
#pragma unroll
      for (int kt = 0; kt < 16; ++kt) {
        const s8v av = __builtin_bit_cast(s8v, a[kt]);
        acc0 = MFMA16(av, bh[0][kt], acc0, 0, 0, 0);
        acc1 = MFMA16(av, bh[1][kt], acc1, 0, 0, 0);
        acc2 = MFMA16(av, bh[2][kt], acc2, 0, 0, 0);
      }

      unsigned hv[4];
#pragma unroll
      for (int r = 0; r < 4; ++r) {
        float rr = fsig(acc0[r] + br);
        float zz = fsig(acc1[r] + bz);
        float nn = ftanh(acc2x[r] + bni + rr * (acc2[r] + bnh));
        float hn = (1.f - zz) * nn + zz * hp[r];
        hp[r] = hn;
        hv[r] = f2bf(hn);
      }

      // publish h1_t: hbuf (drained) + h1pl plane t (lazy; gate s+3 covers)
      u16* pb = hbuf + (size_t)((t + 1) & 1) * kPlane + prod_off;
      u16* qb = h1pl + (size_t)t * kPlane + prod_off;
      store_h_l0(pb + (size_t)(mrow + 0) * 8, pb + (size_t)(mrow + 1) * 8,
                 pb + (size_t)(mrow + 2) * 8, pb + (size_t)(mrow + 3) * 8,
                 qb + (size_t)(mrow + 0) * 8, qb + (size_t)(mrow + 1) * 8,
                 qb + (size_t)(mrow + 2) * 8, qb + (size_t)(mrow + 3) * 8,
                 hv[0], hv[1], hv[2], hv[3]);
      __syncthreads();
      if (tid == 0)
        __hip_atomic_fetch_add(barL0, 1u, __ATOMIC_RELAXED,
                               __HIP_MEMORY_SCOPE_AGENT);
      if (t + 1 < kT) {   // x frags for t+1 fly during next wait phase
        const u16* xb = xpl + (size_t)(t + 1) * kXStep + xoff;
        ax0 = *(const s8v*)xb;
        ax1 = *(const s8v*)(xb + 512);
      }
    }
    // tail: drain ALL remaining stores (every wave), then one extra arrive
    // so barL0 reaches 16*(kT+1) — covers plane kT-1's lazy h1pl stores.
    asm volatile("s_waitcnt vmcnt(0)" ::: "memory");
    __syncthreads();
    if (tid == 0)
      __hip_atomic_fetch_add(barL0, 1u, __ATOMIC_RELAXED,
                             __HIP_MEMORY_SCOPE_AGENT);
  } else {
    // ---- w_ih1 jt-slice -> LDS (once); w_hh1 resident in VGPRs ----
    {
      const u16* src = slab1ih + (size_t)jt * 96 * 512;
      for (int i = tid; i < 96 * 512 / 8; i += 256)
        *(s8v*)&ldsw[i * 8] = *(const s8v*)&src[i * 8];
    }
    s8v bh[3][16];
    {
      const u16* base = slab1hh + (size_t)jt * 96 * 512 + (size_t)lane * 8;
#pragma unroll
      for (int g = 0; g < 3; ++g)
#pragma unroll
        for (int kt = 0; kt < 16; ++kt)
          bh[g][kt] = *(const s8v*)(base + (size_t)((g * 2 + u) * 16 + kt) * 512);
    }
    const float br  = bih1[jg] + bhh1[jg];
    const float bz  = bih1[512 + jg] + bhh1[512 + jg];
    const float bni = bih1[1024 + jg], bnh = bhh1[1024 + jg];
    float hp[4] = {0.f, 0.f, 0.f, 0.f};

    const u16* h1base = h1pl + cons_off;   // plane s at + s*kPlane
    i4v a1[16];                            // persistent across steps

    for (int s = 0; s < kT; ++s) {
      if (tid == 0 && s) {
        unsigned tgt = 16u * (unsigned)s;
        int guard = 0;
        while (__hip_atomic_load(barL1, __ATOMIC_RELAXED,
                                 __HIP_MEMORY_SCOPE_AGENT) < tgt
               && ++guard < (1 << 21))
          __builtin_amdgcn_s_sleep(1);
      } else if (tid == 64) {
        unsigned sg = (unsigned)((s + 3 <= kT + 1) ? (s + 3) : (kT + 1));
        unsigned tgt = 16u * sg;
        int guard = 0;
        while (__hip_atomic_load(barL0, __ATOMIC_RELAXED,
                                 __HIP_MEMORY_SCOPE_AGENT) < tgt
               && ++guard < (1 << 21))
          __builtin_amdgcn_s_sleep(1);
      }
      __syncthreads();   // also orders the LDS fill before first ds_read

      // step 0: a1 (plane 0) has no prior prefetch — issue it FIRST so the
      // vmcnt(16) pairing below completes it while a2 stays in flight.
      if (s == 0) load16_nw(h1base, a1);

      // issue h2_{s-1} loads; vmcnt(16) completes ONLY the older a1 set;
      // ih MFMAs then run under a2's LLC latency (r7-verified pairing).
      i4v a2[16];
      load16_nw(hbuf + (size_t)(2 + (s & 1)) * kPlane + cons_off, a2);
      asm volatile("s_waitcnt vmcnt(16)" ::: "memory");
      __builtin_amdgcn_sched_barrier(0);   // rule #18: pin ih MFMAs below

      const f4v z4 = {0.f, 0.f, 0.f, 0.f};
      f4v acc0 = z4, acc1 = z4, acc2 = z4, acc2x = z4;
#pragma unroll
      for (int kt = 0; kt < 16; ++kt) {
        const s8v b0 = *(const s8v*)&ldsw[(size_t)((0 + u) * 16 + kt) * 512 + lane * 8];
        const s8v b1 = *(const s8v*)&ldsw[(size_t)((2 + u) * 16 + kt) * 512 + lane * 8];
        const s8v b2 = *(const s8v*)&ldsw[(size_t)((4 + u) * 16 + kt) * 512 + lane * 8];
        const s8v av = __builtin_bit_cast(s8v, a1[kt]);
        acc0  = MFMA16(av, b0, acc0, 0, 0, 0);
        acc1  = MFMA16(av, b1, acc1, 0, 0, 0);
        acc2x = MFMA16(av, b2, acc2x, 0, 0, 0);
      }
      asm volatile("s_waitcnt vmcnt(0)" ::: "memory");
      __builtin_amdgcn_sched_barrier(0);   // rule #18: pin hh MFMAs below
#pragma unroll
      for (int kt = 0; kt < 16; ++kt) {
        const s8v av = __builtin_bit_cast(s8v, a2[kt]);
        acc0 = MFMA16(av, bh[0][kt], acc0, 0, 0, 0);
        acc1 = MFMA16(av, bh[1][kt], acc1, 0, 0, 0);
        acc2 = MFMA16(av, bh[2][kt], acc2, 0, 0, 0);
      }

      unsigned hv[4];
#pragma unroll
      for (int r = 0; r < 4; ++r) {
        float rr = fsig(acc0[r] + br);
        float zz = fsig(acc1[r] + bz);
        float nn = ftanh(acc2x[r] + bni + rr * (acc2[r] + bnh));
        float hn = (1.f - zz) * nn + zz * hp[r];
        hp[r] = hn;
        hv[r] = f2bf(hn);
      }

      u16* pb = hbuf + (size_t)(2 + ((s + 1) & 1)) * kPlane + prod_off;
      store_h_l1(pb + (size_t)(mrow + 0) * 8, pb + (size_t)(mrow + 1) * 8,
                 pb + (size_t)(mrow + 2) * 8, pb + (size_t)(mrow + 3) * 8,
                 hv[0], hv[1], hv[2], hv[3]);
      __syncthreads();
      if (tid == 0)
        __hip_atomic_fetch_add(barL1, 1u, __ATOMIC_RELAXED,
                               __HIP_MEMORY_SCOPE_AGENT);
      // prefetch a1 for s+1 (plane s+1; THIS step's gate covered its lazy
      // drain via L0's arrive(s+2)); flies across next wait phase.
      if (s + 1 < kT)
        load16_nw(h1base + (size_t)(s + 1) * kPlane, a1);
    }

    // final h2 -> carry (fp32) for the FC
#pragma unroll
    for (int r = 0; r < 4; ++r)
      carry[(size_t)(bbase + r) * 512 + jg] = hp[r];
  }
}

// ---------------------------------------------------------------------------
__global__ __launch_bounds__(128)
void fc_kernel(const float* __restrict__ h, const float* __restrict__ wfc,
               const float* __restrict__ bfc, float* __restrict__ out) {
  const int b = blockIdx.x;
  const int n = threadIdx.x;
  const float* hrow = h + (size_t)b * kH;
  const float* wrow = wfc + (size_t)n * kH;
  float acc = 0.f;
#pragma unroll 4
  for (int k = 0; k < kH; k += 4) {
    const float4 hv = *(const float4*)&hrow[k];
    const float4 wv = *(const float4*)&wrow[k];
    acc = fmaf(hv.x, wv.x, acc); acc = fmaf(hv.y, wv.y, acc);
    acc = fmaf(hv.z, wv.z, acc); acc = fmaf(hv.w, wv.w, acc);
  }
  out[(size_t)b * kNOUT + n] = acc + bfc[n];
}

// ---------------------------------------------------------------------------
extern "C" void kernel_launch(void* const* d_in, const int* in_sizes, int n_in,
                              void* d_out, int out_size, void* d_ws, size_t ws_size,
                              hipStream_t stream) {
  const float* x     = (const float*)d_in[0];
  const float* w_ih0 = (const float*)d_in[1];
  const float* w_hh0 = (const float*)d_in[2];
  const float* b_ih0 = (const float*)d_in[3];
  const float* b_hh0 = (const float*)d_in[4];
  const float* w_ih1 = (const float*)d_in[5];
  const float* w_hh1 = (const float*)d_in[6];
  const float* b_ih1 = (const float*)d_in[7];
  const float* b_hh1 = (const float*)d_in[8];
  const float* w_fc  = (const float*)d_in[9];
  const float* b_fc  = (const float*)d_in[10];
  float* out = (float*)d_out;

  // workspace: slabs 4.7 MB + xpl 16.8 MB + h1pl 128 MB (write-once) +
  // hbuf 1 MB + carry 0.5 MB + bar ~= 151 MB total.
  char* p = (char*)d_ws;
  auto carve = [&](size_t bytes) {
    char* r = p; p += (bytes + 255) & ~(size_t)255; return r;
  };
  u16* slab0hh = (u16*)carve((size_t)kG3 * kH * 2);
  u16* slab1hh = (u16*)carve((size_t)kG3 * kH * 2);
  u16* slab1ih = (u16*)carve((size_t)kG3 * kH * 2);
  u16* slab0ih = (u16*)carve((size_t)kG3 * kDIN * 2);
  u16* xpl     = (u16*)carve((size_t)kT * kXStep * 2);
  u16* h1pl    = (u16*)carve((size_t)kT * kPlane * 2);   // 128 MB, write-once
  u16* hbuf    = (u16*)carve(4 * (size_t)kPlane * 2);
  float* carry = (float*)carve((size_t)kB * kH * 4);
  unsigned* bar = (unsigned*)carve(16 * 64 * sizeof(unsigned));

  // prologue: swizzles + zero h planes + barrier counters
  build_wslab<<<384, 256, 0, stream>>>(w_hh0, slab0hh);
  build_wslab<<<384, 256, 0, stream>>>(w_hh1, slab1hh);
  build_wslab<<<384, 256, 0, stream>>>(w_ih1, slab1ih);
  build_wslab_ih0<<<48, 256, 0, stream>>>(w_ih0, slab0ih);
  build_xplane<<<4096, 256, 0, stream>>>(x, xpl);
  hipMemsetAsync(hbuf, 0, 4 * (size_t)kPlane * 2, stream);
  hipMemsetAsync(bar, 0, 16 * 64 * sizeof(unsigned), stream);

  // the whole 2-layer recurrence in ONE persistent dispatch
  rec_all<<<dim3(256), dim3(256), 0, stream>>>(
      bar, xpl, slab0hh, slab0ih, slab1hh, slab1ih,
      b_ih0, b_hh0, b_ih1, b_hh1, h1pl, hbuf, carry);

  // final FC on layer-1 terminal state
  fc_kernel<<<dim3(kB), dim3(kNOUT), 0, stream>>>(carry, w_fc, b_fc, out);
}